// Round 17
// baseline (390.638 us; speedup 1.0000x reference)
//
#include <hip/hip_runtime.h>
#include <math.h>

#define BB    4
#define NN    1024
#define DIM   512
#define HH    16
#define DH    13
#define INNER 208
#define QKVN  624
#define QKVNP 640
#define KOUTP 224
#define FFH   2048
#define ROWS  4096

typedef __attribute__((ext_vector_type(8))) short short8v;
typedef __attribute__((ext_vector_type(4))) float f32x4;

// softmax scale * log2(e), baked into Q at scatter time (R17)
#define QSCL (0.27735009811261457f * 1.4426950408889634f)

__device__ __forceinline__ unsigned short f2bf(float f) {
    union { float f; unsigned int u; } x; x.f = f;
    unsigned int u = x.u + 0x7FFFu + ((x.u >> 16) & 1u);
    return (unsigned short)(u >> 16);
}
__device__ __forceinline__ float gelu_exact(float x) {
    return 0.5f * x * (1.0f + erff(x * 0.70710678118654752f));
}

// ---------------------------------------------------------------------------
// Mask normalization (validated R4+); emits rowmask, float table, ones table.
// ---------------------------------------------------------------------------
__global__ __launch_bounds__(1024) void mask_detect_kernel(
        const unsigned char* __restrict__ mraw, int* __restrict__ flag) {
    __shared__ int any;
    if (threadIdx.x == 0) any = 0;
    __syncthreads();
    int t = threadIdx.x;
    int v = mraw[4 * t + 1] | mraw[4 * t + 2] | mraw[4 * t + 3];
    if (v) atomicOr(&any, 1);
    __syncthreads();
    if (threadIdx.x == 0) *flag = any;
}

__global__ __launch_bounds__(256) void mask_convert_kernel(
        const void* __restrict__ mraw, const int* __restrict__ flag,
        int* __restrict__ rowmask, float* __restrict__ maskfb,
        float* __restrict__ onesfb) {
    int i = blockIdx.x * 256 + threadIdx.x;
    int v;
    if (*flag) v = ((const unsigned char*)mraw)[i] != 0;
    else       v = ((const int*)mraw)[i] != 0;
    rowmask[i] = v;
    maskfb[i] = v ? 1.0f : 0.0f;
    if (i < NN) onesfb[i] = 1.0f;
}

// ---------------------------------------------------------------------------
// One-time pad zeroing (R16 validated)
// ---------------------------------------------------------------------------
__global__ __launch_bounds__(256) void padzero_kernel(
        unsigned short* __restrict__ Qb, unsigned short* __restrict__ Kb,
        unsigned short* __restrict__ Vtb, unsigned short* __restrict__ V2t) {
    int idx = blockIdx.x * 256 + threadIdx.x;
    if (idx < 65536) {
        unsigned short* p = Qb + (size_t)idx * 16 + 13;
        p[0] = 0; p[1] = 0; p[2] = 0;
    } else if (idx < 131072) {
        unsigned short* p = Kb + (size_t)(idx - 65536) * 16 + 13;
        p[0] = 0; p[1] = 0; p[2] = 0;
    } else if (idx < 155648) {
        int i = idx - 131072;
        int bh = i / 384, r = (i >> 7) % 3, c = i & 127;
        *(uint4*)(Vtb + ((size_t)(bh * 16 + 13 + r) * 1024 + c * 8)) =
            (uint4){0u, 0u, 0u, 0u};
    } else if (idx < 180224) {
        int i = idx - 155648;
        int b = i / 6144, r = (i >> 7) % 48, c = i & 127;
        *(uint4*)(V2t + ((size_t)(b * 256 + 208 + r) * 1024 + c * 8)) =
            (uint4){0u, 0u, 0u, 0u};
    }
}

// ---------------------------------------------------------------------------
// Weight transpose-convert (validated R7+)
// ---------------------------------------------------------------------------
__global__ __launch_bounds__(256) void convw_kernel(
        const float* __restrict__ src, unsigned short* __restrict__ dst,
        int srcK, int srcN, int dstK, int dstN) {
    __shared__ float t[64][65];
    const int n0 = blockIdx.x * 64, k0 = blockIdx.y * 64;
    const int tq = threadIdx.x & 15, tr = threadIdx.x >> 4;
#pragma unroll
    for (int it = 0; it < 4; ++it) {
        int kl = tr + it * 16;
        int kg = k0 + kl;
        int ng = n0 + tq * 4;
        float4 v = {0.f, 0.f, 0.f, 0.f};
        if (kg < srcK) {
            const float* sp = src + (size_t)kg * srcN;
            if (ng + 3 < srcN) v = *(const float4*)(sp + ng);
            else {
                if (ng + 0 < srcN) v.x = sp[ng + 0];
                if (ng + 1 < srcN) v.y = sp[ng + 1];
                if (ng + 2 < srcN) v.z = sp[ng + 2];
                if (ng + 3 < srcN) v.w = sp[ng + 3];
            }
        }
        t[kl][tq * 4 + 0] = v.x; t[kl][tq * 4 + 1] = v.y;
        t[kl][tq * 4 + 2] = v.z; t[kl][tq * 4 + 3] = v.w;
    }
    __syncthreads();
#pragma unroll
    for (int it = 0; it < 4; ++it) {
        int nl = tr + it * 16;
        int ng = n0 + nl;
        int kg = k0 + tq * 4;
        if (ng < dstN && kg < dstK) {
            ushort4 o;
            o.x = f2bf(t[tq * 4 + 0][nl]); o.y = f2bf(t[tq * 4 + 1][nl]);
            o.z = f2bf(t[tq * 4 + 2][nl]); o.w = f2bf(t[tq * 4 + 3][nl]);
            *(ushort4*)(dst + (size_t)ng * dstK + kg) = o;
        }
    }
}

__global__ __launch_bounds__(256) void convx_kernel(
        const float* __restrict__ src, unsigned short* __restrict__ dst, int n8) {
    int idx = blockIdx.x * 256 + threadIdx.x;
    if (idx >= n8) return;
    float4 a = ((const float4*)src)[idx * 2];
    float4 b = ((const float4*)src)[idx * 2 + 1];
    uint4 o;
    o.x = (unsigned)f2bf(a.x) | ((unsigned)f2bf(a.y) << 16);
    o.y = (unsigned)f2bf(a.z) | ((unsigned)f2bf(a.w) << 16);
    o.z = (unsigned)f2bf(b.x) | ((unsigned)f2bf(b.y) << 16);
    o.w = (unsigned)f2bf(b.z) | ((unsigned)f2bf(b.w) << 16);
    ((uint4*)dst)[idx] = o;
}

__global__ __launch_bounds__(256) void zpad_kernel(unsigned short* __restrict__ attnout) {
    int idx = blockIdx.x * 256 + threadIdx.x;
    int row = idx >> 4, c = INNER + (idx & 15);
    attnout[(size_t)row * KOUTP + c] = 0;
}

__global__ __launch_bounds__(256) void adjmask_kernel(
        const float* __restrict__ adj, const int* __restrict__ rmask,
        unsigned short* __restrict__ adjbf) {
    int idx = blockIdx.x * 256 + threadIdx.x;
    int j8 = idx & 127;
    int row = idx >> 7;
    int b = row >> 10;
    int mi = rmask[row];
    const float* ap = adj + (size_t)row * NN + j8 * 8;
    const int* rm = rmask + (b << 10) + j8 * 8;
    float4 a0 = *(const float4*)ap, a1 = *(const float4*)(ap + 4);
    unsigned short o[8];
    o[0] = (mi && rm[0]) ? f2bf(a0.x) : 0;
    o[1] = (mi && rm[1]) ? f2bf(a0.y) : 0;
    o[2] = (mi && rm[2]) ? f2bf(a0.z) : 0;
    o[3] = (mi && rm[3]) ? f2bf(a0.w) : 0;
    o[4] = (mi && rm[4]) ? f2bf(a1.x) : 0;
    o[5] = (mi && rm[5]) ? f2bf(a1.y) : 0;
    o[6] = (mi && rm[6]) ? f2bf(a1.z) : 0;
    o[7] = (mi && rm[7]) ? f2bf(a1.w) : 0;
    uint4 pk;
    pk.x = (unsigned)o[0] | ((unsigned)o[1] << 16);
    pk.y = (unsigned)o[2] | ((unsigned)o[3] << 16);
    pk.z = (unsigned)o[4] | ((unsigned)o[5] << 16);
    pk.w = (unsigned)o[6] | ((unsigned)o[7] << 16);
    *(uint4*)(adjbf + (size_t)row * NN + j8 * 8) = pk;
}

// ---------------------------------------------------------------------------
// MFMA bf16 GEMM (validated R14-R16). EPI 3 scatter: Q rows pre-scaled by
// QSCL (0 when row masked) so attn4's MFMA emits exp2-domain scores directly.
// ---------------------------------------------------------------------------
template<int EPI, int BM, int BN>
__global__ __launch_bounds__(256) void mm_kernel(
        const unsigned short* __restrict__ A, const unsigned short* __restrict__ W,
        const float* __restrict__ bias, void* __restrict__ Cdst,
        int K, int lda, int ldc,
        long long aBatch, long long bBatch, long long cBatch,
        unsigned short* __restrict__ Qb, unsigned short* __restrict__ Kb,
        unsigned short* __restrict__ Vtb, unsigned short* __restrict__ V2t,
        const int* __restrict__ qmask)
{
    constexpr int MF = BM / 32;
    constexpr int NF = BN / 32;
    constexpr int AROUNDS = BM / 64;
    constexpr int BROUNDS = BN / 64;
    __shared__ unsigned short As[BM * 32];
    __shared__ unsigned short Bs[BN * 32];
    const int tid = threadIdx.x;
    const int m0 = blockIdx.y * BM;
    const int n0 = blockIdx.x * BN;
    const int z  = blockIdx.z;

    const int lane = tid & 63;
    const int wv = tid >> 6;
    const int wvbase = wv << 6;
    const int wm = wv >> 1, wn = wv & 1;
    const int lrow = lane & 15, kgrp = lane >> 4;

    f32x4 acc[MF][NF];
#pragma unroll
    for (int i = 0; i < MF; ++i)
#pragma unroll
        for (int j = 0; j < NF; ++j) acc[i][j] = (f32x4){0.f, 0.f, 0.f, 0.f};

    const unsigned short* Ab = A + (size_t)z * aBatch;
    const unsigned short* Wb = W + (size_t)z * bBatch;

    for (int k0 = 0; k0 < K; k0 += 32) {
#pragma unroll
        for (int r = 0; r < AROUNDS; ++r) {
            int c = r * 256 + tid;
            const unsigned short* g = Ab + (size_t)(m0 + (c >> 2)) * lda + k0 + (c & 3) * 8;
            __builtin_amdgcn_global_load_lds((const unsigned int*)g,
                (unsigned int*)&As[(r * 256 + wvbase) * 8], 16, 0, 0);
        }
#pragma unroll
        for (int r = 0; r < BROUNDS; ++r) {
            int c = r * 256 + tid;
            const unsigned short* g = Wb + (size_t)(n0 + (c >> 2)) * K + k0 + (c & 3) * 8;
            __builtin_amdgcn_global_load_lds((const unsigned int*)g,
                (unsigned int*)&Bs[(r * 256 + wvbase) * 8], 16, 0, 0);
        }
        __syncthreads();
        short8v af[MF], bfv[NF];
#pragma unroll
        for (int f = 0; f < MF; ++f)
            af[f] = *(const short8v*)&As[(wm * (BM / 2) + f * 16 + lrow) * 32 + kgrp * 8];
#pragma unroll
        for (int f = 0; f < NF; ++f)
            bfv[f] = *(const short8v*)&Bs[(wn * (BN / 2) + f * 16 + lrow) * 32 + kgrp * 8];
#pragma unroll
        for (int fi = 0; fi < MF; ++fi)
#pragma unroll
            for (int fj = 0; fj < NF; ++fj)
                acc[fi][fj] = __builtin_amdgcn_mfma_f32_16x16x32_bf16(
                    af[fi], bfv[fj], acc[fi][fj], 0, 0, 0);
        __syncthreads();
    }

#pragma unroll
    for (int fi = 0; fi < MF; ++fi) {
#pragma unroll
        for (int fj = 0; fj < NF; ++fj) {
#pragma unroll
            for (int p = 0; p < 4; ++p) {
                int row = m0 + wm * (BM / 2) + fi * 16 + kgrp * 4 + p;
                int col = n0 + wn * (BN / 2) + fj * 16 + lrow;
                float v = acc[fi][fj][p];
                if (EPI == 0) {
                    float* C = (float*)Cdst + (size_t)z * cBatch;
                    if (bias) v += bias[col];
                    C[(size_t)row * ldc + col] = v;
                } else if (EPI == 1) {
                    unsigned short* C = (unsigned short*)Cdst;
                    C[(size_t)row * ldc + col] = f2bf(gelu_exact(v + bias[col]));
                } else if (EPI == 2) {
                    float* C = (float*)Cdst;
                    C[(size_t)row * ldc + col] += v + bias[col];
                } else {
                    if (col < QKVN) {
                        int hh  = col / 39;
                        int rem = col - hh * 39;
                        int sel = rem / 13;
                        int d   = rem - sel * 13;
                        int bb = row >> 10, n = row & (NN - 1);
                        int bh = bb * HH + hh;
                        if (sel == 0) {
                            // pre-scale Q: 0 when row masked -> uniform row
                            float qs = qmask[row] ? QSCL : 0.0f;
                            Qb[((size_t)bh * NN + n) * 16 + d] = f2bf(v * qs);
                        } else if (sel == 1) {
                            int rr = (n & ~31) | (((n >> 2) & 1) << 4)
                                   | (((n >> 3) & 3) << 2) | (n & 3);
                            Kb[((size_t)bh * NN + rr) * 16 + d] = f2bf(v);
                        } else {
                            unsigned short bv = f2bf(v);
                            Vtb[((size_t)bh * 16 + d) * NN + n] = bv;
                            V2t[((size_t)bb * 256 + hh * 13 + d) * NN + n] = bv;
                        }
                    }
                }
            }
        }
    }
}

// ---------------------------------------------------------------------------
// LayerNorm (unchanged)
// ---------------------------------------------------------------------------
template<int BFOUT>
__global__ __launch_bounds__(256) void ln_kernel(
        const float* __restrict__ x, const float* __restrict__ g,
        const float* __restrict__ bta, void* __restrict__ y) {
    const int lane = threadIdx.x & 63;
    const int row = (blockIdx.x * 256 + threadIdx.x) >> 6;
    const float* xp = x + (size_t)row * DIM + lane * 8;
    float4 v0 = *(const float4*)(xp);
    float4 v1 = *(const float4*)(xp + 4);
    float s = v0.x + v0.y + v0.z + v0.w + v1.x + v1.y + v1.z + v1.w;
#pragma unroll
    for (int off = 32; off >= 1; off >>= 1) s += __shfl_xor(s, off);
    float mean = s * (1.0f / DIM);
    float q =
        (v0.x - mean) * (v0.x - mean) + (v0.y - mean) * (v0.y - mean) +
        (v0.z - mean) * (v0.z - mean) + (v0.w - mean) * (v0.w - mean) +
        (v1.x - mean) * (v1.x - mean) + (v1.y - mean) * (v1.y - mean) +
        (v1.z - mean) * (v1.z - mean) + (v1.w - mean) * (v1.w - mean);
#pragma unroll
    for (int off = 32; off >= 1; off >>= 1) q += __shfl_xor(q, off);
    float rstd = rsqrtf(q * (1.0f / DIM) + 1e-5f);
    const int c = lane * 8;
    float4 g0 = *(const float4*)(g + c), g1 = *(const float4*)(g + c + 4);
    float4 b0 = *(const float4*)(bta + c), b1 = *(const float4*)(bta + c + 4);
    float o0 = (v0.x - mean) * rstd * g0.x + b0.x;
    float o1 = (v0.y - mean) * rstd * g0.y + b0.y;
    float o2 = (v0.z - mean) * rstd * g0.z + b0.z;
    float o3 = (v0.w - mean) * rstd * g0.w + b0.w;
    float o4 = (v1.x - mean) * rstd * g1.x + b1.x;
    float o5 = (v1.y - mean) * rstd * g1.y + b1.y;
    float o6 = (v1.z - mean) * rstd * g1.z + b1.z;
    float o7 = (v1.w - mean) * rstd * g1.w + b1.w;
    if (BFOUT) {
        unsigned short* yp = (unsigned short*)y + (size_t)row * DIM + c;
        uint4 o;
        o.x = (unsigned)f2bf(o0) | ((unsigned)f2bf(o1) << 16);
        o.y = (unsigned)f2bf(o2) | ((unsigned)f2bf(o3) << 16);
        o.z = (unsigned)f2bf(o4) | ((unsigned)f2bf(o5) << 16);
        o.w = (unsigned)f2bf(o6) | ((unsigned)f2bf(o7) << 16);
        *(uint4*)yp = o;
    } else {
        float* yp = (float*)y + (size_t)row * DIM + c;
        *(float4*)(yp)     = (float4){o0, o1, o2, o3};
        *(float4*)(yp + 4) = (float4){o4, o5, o6, o7};
    }
}

// ---------------------------------------------------------------------------
// attn4 v3 (R17): Q pre-scaled (no per-score mul), blend via table select
// (no per-score fmaf). w = exp2(min(s,80)) * mult[j].
// ---------------------------------------------------------------------------
__global__ __launch_bounds__(256) void attn4_kernel(
        const unsigned short* __restrict__ Qb, const unsigned short* __restrict__ Kb,
        const unsigned short* __restrict__ Vtb, const float* __restrict__ adjout,
        const int* __restrict__ rmask, const float* __restrict__ maskfb,
        const float* __restrict__ onesfb, unsigned short* __restrict__ attnout) {
    const int tid = threadIdx.x;
    const int qt = blockIdx.x, h = blockIdx.y, b = blockIdx.z;
    const int bh = b * HH + h;
    const int wv = tid >> 6, lane = tid & 63;
    const int lrow = lane & 15, g = lane >> 4;
    const int q = qt * 64 + wv * 16 + lrow;
    const int mi = rmask[b * NN + q];
    const float* mult = mi ? (maskfb + b * NN) : onesfb;

    short8v qf = (short8v){0, 0, 0, 0, 0, 0, 0, 0};
    if (g < 2)
        qf = *(const short8v*)(Qb + ((size_t)bh * NN + q) * 16 + g * 8);

    const unsigned short* Kbh = Kb + (size_t)bh * NN * 16;
    const unsigned short* Vrow = Vtb + ((size_t)bh * 16 + lrow) * NN;

    f32x4 oacc = (f32x4){0.f, 0.f, 0.f, 0.f};
    float zacc = 0.0f;

    for (int t = 0; t < 32; ++t) {
        const int j0 = t * 32;
        short8v kf0 = (short8v){0, 0, 0, 0, 0, 0, 0, 0};
        short8v kf1 = (short8v){0, 0, 0, 0, 0, 0, 0, 0};
        if (g < 2) {
            kf0 = *(const short8v*)(Kbh + (size_t)(j0 + lrow) * 16 + g * 8);
            kf1 = *(const short8v*)(Kbh + (size_t)(j0 + 16 + lrow) * 16 + g * 8);
        }
        f32x4 s0 = (f32x4){0.f, 0.f, 0.f, 0.f};
        f32x4 s1 = (f32x4){0.f, 0.f, 0.f, 0.f};
        s0 = __builtin_amdgcn_mfma_f32_16x16x32_bf16(kf0, qf, s0, 0, 0, 0);
        s1 = __builtin_amdgcn_mfma_f32_16x16x32_bf16(kf1, qf, s1, 0, 0, 0);
        float4 m0 = *(const float4*)&mult[j0 + g * 8];
        float4 m1 = *(const float4*)&mult[j0 + g * 8 + 4];
        float w0 = exp2f(fminf(s0[0], 80.f)) * m0.x;
        float w1 = exp2f(fminf(s0[1], 80.f)) * m0.y;
        float w2 = exp2f(fminf(s0[2], 80.f)) * m0.z;
        float w3 = exp2f(fminf(s0[3], 80.f)) * m0.w;
        float w4 = exp2f(fminf(s1[0], 80.f)) * m1.x;
        float w5 = exp2f(fminf(s1[1], 80.f)) * m1.y;
        float w6 = exp2f(fminf(s1[2], 80.f)) * m1.z;
        float w7 = exp2f(fminf(s1[3], 80.f)) * m1.w;
        zacc += ((w0 + w1) + (w2 + w3)) + ((w4 + w5) + (w6 + w7));
        unsigned p01, p23, p45, p67;
        asm("v_cvt_pk_bf16_f32 %0, %1, %2" : "=v"(p01) : "v"(w0), "v"(w1));
        asm("v_cvt_pk_bf16_f32 %0, %1, %2" : "=v"(p23) : "v"(w2), "v"(w3));
        asm("v_cvt_pk_bf16_f32 %0, %1, %2" : "=v"(p45) : "v"(w4), "v"(w5));
        asm("v_cvt_pk_bf16_f32 %0, %1, %2" : "=v"(p67) : "v"(w6), "v"(w7));
        union { uint4 u4; short8v s8; } pu;
        pu.u4 = (uint4){p01, p23, p45, p67};
        short8v vf = *(const short8v*)(Vrow + j0 + g * 8);
        oacc = __builtin_amdgcn_mfma_f32_16x16x32_bf16(vf, pu.s8, oacc, 0, 0, 0);
    }

    zacc += __shfl_xor(zacc, 16);
    zacc += __shfl_xor(zacc, 32);
    float inv = 1.0f / zacc;

    const float* arow = adjout + ((size_t)(b * NN + q)) * 256 + h * 13;
    unsigned short* orow = attnout + (size_t)(b * NN + q) * KOUTP + h * 13;
#pragma unroll
    for (int p = 0; p < 4; ++p) {
        int d = 4 * g + p;
        if (d < 13)
            orow[d] = f2bf(fmaf(oacc[p], inv, 0.5f * arow[d]));
    }
}

// ---------------------------------------------------------------------------
// Coalesced pool (unchanged)
// ---------------------------------------------------------------------------
__global__ __launch_bounds__(256) void pool1_kernel(
        const float* __restrict__ xn, float* __restrict__ poolpart) {
    __shared__ float red[256][4];
    const int ch = blockIdx.x, b = blockIdx.y;
    const int c4 = threadIdx.x & 127, p = threadIdx.x >> 7;
    const float* base = xn + ((size_t)(b * NN) + ch * 64 + p) * DIM + c4 * 4;
    float4 s = {0.f, 0.f, 0.f, 0.f};
    for (int r = 0; r < 32; ++r) {
        float4 v = *(const float4*)(base + (size_t)r * 2 * DIM);
        s.x += v.x; s.y += v.y; s.z += v.z; s.w += v.w;
    }
    *(float4*)red[threadIdx.x] = s;
    __syncthreads();
    if (threadIdx.x < 128) {
        float4 a = *(float4*)red[threadIdx.x];
        float4 c = *(float4*)red[threadIdx.x + 128];
        float4 o = {a.x + c.x, a.y + c.y, a.z + c.z, a.w + c.w};
        *(float4*)(poolpart + (size_t)(b * 16 + ch) * DIM + c4 * 4) = o;
    }
}

__global__ __launch_bounds__(256) void pool2_kernel(
        const float* __restrict__ poolpart, float* __restrict__ pooled) {
    int c = blockIdx.x * 256 + threadIdx.x;
    int b = c >> 9, col = c & 511;
    float s = 0.f;
    for (int ch = 0; ch < 16; ++ch)
        s += poolpart[(size_t)(b * 16 + ch) * DIM + col];
    pooled[c] = s * (1.0f / NN);
}

// ---------------------------------------------------------------------------
// Final MLP split-K (validated R9)
// ---------------------------------------------------------------------------
__global__ __launch_bounds__(256) void ffo1a_kernel(
        const float* __restrict__ pooled, const float* __restrict__ w,
        float* __restrict__ part) {
    int n = blockIdx.x * 256 + threadIdx.x;
    int kc = blockIdx.y;
    float s0 = 0.f, s1 = 0.f, s2 = 0.f, s3 = 0.f;
    for (int k = kc * 128; k < kc * 128 + 128; ++k) {
        float wv = w[(size_t)k * FFH + n];
        s0 = fmaf(pooled[k], wv, s0);
        s1 = fmaf(pooled[512 + k], wv, s1);
        s2 = fmaf(pooled[1024 + k], wv, s2);
        s3 = fmaf(pooled[1536 + k], wv, s3);
    }
    part[(size_t)(kc * 4 + 0) * FFH + n] = s0;
    part[(size_t)(kc * 4 + 1) * FFH + n] = s1;
    part[(size_t)(kc * 4 + 2) * FFH + n] = s2;
    part[(size_t)(kc * 4 + 3) * FFH + n] = s3;
}

__global__ __launch_bounds__(256) void ffo1b_kernel(
        const float* __restrict__ part, const float* __restrict__ bias,
        float* __restrict__ ffoh) {
    int c = blockIdx.x * 256 + threadIdx.x;
    int b = c >> 11, n = c & 2047;
    float s = bias[n];
#pragma unroll
    for (int kc = 0; kc < 4; ++kc)
        s += part[(size_t)(kc * 4 + b) * FFH + n];
    ffoh[c] = gelu_exact(s);
}

__global__ __launch_bounds__(256) void ffo2a_kernel(
        const float* __restrict__ ffoh, const float* __restrict__ w,
        float* __restrict__ part) {
    int n = blockIdx.x * 256 + threadIdx.x;
    int kc = blockIdx.y;
    float s0 = 0.f, s1 = 0.f, s2 = 0.f, s3 = 0.f;
    for (int k = kc * 128; k < kc * 128 + 128; ++k) {
        float wv = w[(size_t)k * DIM + n];
        s0 = fmaf(ffoh[k], wv, s0);
        s1 = fmaf(ffoh[2048 + k], wv, s1);
        s2 = fmaf(ffoh[4096 + k], wv, s2);
        s3 = fmaf(ffoh[6144 + k], wv, s3);
    }
    part[(size_t)(kc * 4 + 0) * DIM + n] = s0;
    part[(size_t)(kc * 4 + 1) * DIM + n] = s1;
    part[(size_t)(kc * 4 + 2) * DIM + n] = s2;
    part[(size_t)(kc * 4 + 3) * DIM + n] = s3;
}

__global__ __launch_bounds__(256) void ffo2b_kernel(
        const float* __restrict__ part, const float* __restrict__ bias,
        float* __restrict__ out) {
    int c = blockIdx.x * 256 + threadIdx.x;
    int b = c >> 9, n = c & 511;
    float s = bias[n];
#pragma unroll
    for (int kc = 0; kc < 16; ++kc)
        s += part[(size_t)(kc * 4 + b) * DIM + n];
    out[c] = s;
}

// ---------------------------------------------------------------------------
// Launch. 256 MiB ws proven (R15); no-alias layout, high-water ~71.7 MB.
// ---------------------------------------------------------------------------
extern "C" void kernel_launch(void* const* d_in, const int* in_sizes, int n_in,
                              void* d_out, int out_size, void* d_ws, size_t ws_size,
                              hipStream_t stream) {
    const float* x       = (const float*)d_in[0];
    const void*  mraw    = d_in[1];
    const float* adj     = (const float*)d_in[2];
    const float* embed_w = (const float*)d_in[3];
    const float* embed_b = (const float*)d_in[4];
    const float* ln1_g   = (const float*)d_in[5];
    const float* ln1_b   = (const float*)d_in[6];
    const float* qkv_w   = (const float*)d_in[7];
    const float* out_w   = (const float*)d_in[8];
    const float* out_b   = (const float*)d_in[9];
    const float* ln2_g   = (const float*)d_in[10];
    const float* ln2_b   = (const float*)d_in[11];
    const float* ff1_w   = (const float*)d_in[12];
    const float* ff1_b   = (const float*)d_in[13];
    const float* ff2_w   = (const float*)d_in[14];
    const float* ff2_b   = (const float*)d_in[15];
    const float* lnout_g = (const float*)d_in[16];
    const float* lnout_b = (const float*)d_in[17];
    const float* ffo1_w  = (const float*)d_in[18];
    const float* ffo1_b  = (const float*)d_in[19];
    const float* ffo2_w  = (const float*)d_in[20];
    const float* ffo2_b  = (const float*)d_in[21];

    char* ws = (char*)d_ws;
    float*          h       = (float*)(ws + 0);
    unsigned short* xnbf    = (unsigned short*)(ws + 8388608);
    unsigned short* adjbf   = (unsigned short*)(ws + 12582912);
    unsigned short* Qb      = (unsigned short*)(ws + 20971520);
    unsigned short* Kb      = (unsigned short*)(ws + 23068672);
    unsigned short* Vtb     = (unsigned short*)(ws + 25165824);
    unsigned short* V2t     = (unsigned short*)(ws + 27262976);
    float*          adjout  = (float*)(ws + 29360128);
    unsigned short* ffh     = (unsigned short*)(ws + 33554432);
    float*          xnf     = (float*)(ws + 50331648);
    unsigned short* attnout = (unsigned short*)(ws + 58720256);
    unsigned short* embedwt = (unsigned short*)(ws + 60555264);
    unsigned short* qkvwt   = (unsigned short*)(ws + 61079552);
    unsigned short* outwt   = (unsigned short*)(ws + 62390272);
    unsigned short* ff1wt   = (unsigned short*)(ws + 62849024);
    unsigned short* ff2wt   = (unsigned short*)(ws + 67043328);
    float*          poolpart= (float*)(ws + 71237632);
    float*          pooled  = (float*)(ws + 71368704);
    float*          ffoh    = (float*)(ws + 71376896);
    float*          part1   = (float*)(ws + 71409664);
    float*          part2   = (float*)(ws + 71540736);
    int*            rowmask = (int*)(ws + 71671808);
    float*          maskfb  = (float*)(ws + 71688192);
    float*          onesfb  = (float*)(ws + 71704576);           // 4 KB
    int*            flag    = (int*)(ws + 71708672);

    mask_detect_kernel<<<1, 1024, 0, stream>>>((const unsigned char*)mraw, flag);
    mask_convert_kernel<<<16, 256, 0, stream>>>(mraw, flag, rowmask, maskfb, onesfb);
    convx_kernel<<<1024, 256, 0, stream>>>(x, xnbf, ROWS * DIM / 8);
    convw_kernel<<<dim3(8, 8), 256, 0, stream>>>(embed_w, embedwt, 512, 512, 512, 512);
    for (int l = 0; l < 2; ++l) {
        convw_kernel<<<dim3(10, 8), 256, 0, stream>>>(qkv_w + (size_t)l * 512 * 624,
            qkvwt + (size_t)l * QKVNP * 512, 512, 624, 512, QKVNP);
        convw_kernel<<<dim3(8, 4), 256, 0, stream>>>(out_w + (size_t)l * 208 * 512,
            outwt + (size_t)l * 512 * KOUTP, 208, 512, KOUTP, 512);
        convw_kernel<<<dim3(32, 8), 256, 0, stream>>>(ff1_w + (size_t)l * 512 * 2048,
            ff1wt + (size_t)l * 2048 * 512, 512, 2048, 512, 2048);
        convw_kernel<<<dim3(8, 32), 256, 0, stream>>>(ff2_w + (size_t)l * 512 * 2048,
            ff2wt + (size_t)l * 512 * 2048, 2048, 512, 2048, 512);
    }
    zpad_kernel<<<256, 256, 0, stream>>>(attnout);
    padzero_kernel<<<704, 256, 0, stream>>>(Qb, Kb, Vtb, V2t);
    adjmask_kernel<<<2048, 256, 0, stream>>>(adj, rowmask, adjbf);

    mm_kernel<0, 64, 64><<<dim3(8, 64, 1), 256, 0, stream>>>(
        xnbf, embedwt, embed_b, h, 512, 512, 512, 0, 0, 0,
        nullptr, nullptr, nullptr, nullptr, nullptr);

    for (int l = 0; l < 2; ++l) {
        ln_kernel<1><<<1024, 256, 0, stream>>>(h, ln1_g + l * DIM, ln1_b + l * DIM, xnbf);
        mm_kernel<3, 64, 64><<<dim3(10, 64, 1), 256, 0, stream>>>(
            xnbf, qkvwt + (size_t)l * QKVNP * 512, nullptr, nullptr,
            512, 512, 0, 0, 0, 0, Qb, Kb, Vtb, V2t, rowmask);
        mm_kernel<0, 64, 64><<<dim3(4, 16, 4), 256, 0, stream>>>(
            adjbf, V2t, nullptr, adjout, 1024, 1024, 256,
            (long long)NN * NN, (long long)256 * NN, (long long)NN * 256,
            nullptr, nullptr, nullptr, nullptr, nullptr);
        attn4_kernel<<<dim3(16, 16, 4), 256, 0, stream>>>(
            Qb, Kb, Vtb, adjout, rowmask, maskfb, onesfb, attnout);
        mm_kernel<2, 64, 64><<<dim3(8, 64, 1), 256, 0, stream>>>(
            attnout, outwt + (size_t)l * 512 * KOUTP, out_b + l * DIM, h,
            KOUTP, KOUTP, 512, 0, 0, 0, nullptr, nullptr, nullptr, nullptr, nullptr);
        ln_kernel<1><<<1024, 256, 0, stream>>>(h, ln2_g + l * DIM, ln2_b + l * DIM, xnbf);
        mm_kernel<1, 128, 128><<<dim3(16, 32, 1), 256, 0, stream>>>(
            xnbf, ff1wt + (size_t)l * 2048 * 512, ff1_b + l * FFH, ffh,
            512, 512, 2048, 0, 0, 0, nullptr, nullptr, nullptr, nullptr, nullptr);
        mm_kernel<2, 64, 64><<<dim3(8, 64, 1), 256, 0, stream>>>(
            ffh, ff2wt + (size_t)l * 512 * 2048, ff2_b + l * DIM, h,
            2048, 2048, 512, 0, 0, 0, nullptr, nullptr, nullptr, nullptr, nullptr);
    }

    ln_kernel<0><<<1024, 256, 0, stream>>>(h, lnout_g, lnout_b, xnf);
    pool1_kernel<<<dim3(16, 4), 256, 0, stream>>>(xnf, poolpart);
    pool2_kernel<<<8, 256, 0, stream>>>(poolpart, pooled);
    ffo1a_kernel<<<dim3(8, 4), 256, 0, stream>>>(pooled, ffo1_w, part1);
    ffo1b_kernel<<<32, 256, 0, stream>>>(part1, ffo1_b, ffoh);
    ffo2a_kernel<<<dim3(2, 16), 256, 0, stream>>>(ffoh, ffo2_w, part2);
    ffo2b_kernel<<<8, 256, 0, stream>>>(part2, ffo2_b, (float*)d_out);
}

// Round 18
// 381.802 us; speedup vs baseline: 1.0231x; 1.0231x over previous
//
#include <hip/hip_runtime.h>
#include <math.h>

#define BB    4
#define NN    1024
#define DIM   512
#define HH    16
#define DH    13
#define INNER 208
#define QKVN  624
#define QKVNP 640
#define KOUTP 224
#define FFH   2048
#define ROWS  4096

typedef __attribute__((ext_vector_type(8))) short short8v;
typedef __attribute__((ext_vector_type(4))) float f32x4;

// softmax scale * log2(e), baked into Q at scatter time (R17, validated)
#define QSCL (0.27735009811261457f * 1.4426950408889634f)

__device__ __forceinline__ unsigned short f2bf(float f) {
    union { float f; unsigned int u; } x; x.f = f;
    unsigned int u = x.u + 0x7FFFu + ((x.u >> 16) & 1u);
    return (unsigned short)(u >> 16);
}
__device__ __forceinline__ float gelu_exact(float x) {
    return 0.5f * x * (1.0f + erff(x * 0.70710678118654752f));
}

// ---------------------------------------------------------------------------
// Mask normalization (validated R4+)
// ---------------------------------------------------------------------------
__global__ __launch_bounds__(1024) void mask_detect_kernel(
        const unsigned char* __restrict__ mraw, int* __restrict__ flag) {
    __shared__ int any;
    if (threadIdx.x == 0) any = 0;
    __syncthreads();
    int t = threadIdx.x;
    int v = mraw[4 * t + 1] | mraw[4 * t + 2] | mraw[4 * t + 3];
    if (v) atomicOr(&any, 1);
    __syncthreads();
    if (threadIdx.x == 0) *flag = any;
}

__global__ __launch_bounds__(256) void mask_convert_kernel(
        const void* __restrict__ mraw, const int* __restrict__ flag,
        int* __restrict__ rowmask, float* __restrict__ maskfb) {
    int i = blockIdx.x * 256 + threadIdx.x;
    int v;
    if (*flag) v = ((const unsigned char*)mraw)[i] != 0;
    else       v = ((const int*)mraw)[i] != 0;
    rowmask[i] = v;
    maskfb[i] = v ? 1.0f : 0.0f;
}

// ---------------------------------------------------------------------------
// One-time pad zeroing (R16 validated)
// ---------------------------------------------------------------------------
__global__ __launch_bounds__(256) void padzero_kernel(
        unsigned short* __restrict__ Qb, unsigned short* __restrict__ Kb,
        unsigned short* __restrict__ Vtb, unsigned short* __restrict__ V2t) {
    int idx = blockIdx.x * 256 + threadIdx.x;
    if (idx < 65536) {
        unsigned short* p = Qb + (size_t)idx * 16 + 13;
        p[0] = 0; p[1] = 0; p[2] = 0;
    } else if (idx < 131072) {
        unsigned short* p = Kb + (size_t)(idx - 65536) * 16 + 13;
        p[0] = 0; p[1] = 0; p[2] = 0;
    } else if (idx < 155648) {
        int i = idx - 131072;
        int bh = i / 384, r = (i >> 7) % 3, c = i & 127;
        *(uint4*)(Vtb + ((size_t)(bh * 16 + 13 + r) * 1024 + c * 8)) =
            (uint4){0u, 0u, 0u, 0u};
    } else if (idx < 180224) {
        int i = idx - 155648;
        int b = i / 6144, r = (i >> 7) % 48, c = i & 127;
        *(uint4*)(V2t + ((size_t)(b * 256 + 208 + r) * 1024 + c * 8)) =
            (uint4){0u, 0u, 0u, 0u};
    }
}

// ---------------------------------------------------------------------------
// Weight transpose-convert (validated R7+)
// ---------------------------------------------------------------------------
__global__ __launch_bounds__(256) void convw_kernel(
        const float* __restrict__ src, unsigned short* __restrict__ dst,
        int srcK, int srcN, int dstK, int dstN) {
    __shared__ float t[64][65];
    const int n0 = blockIdx.x * 64, k0 = blockIdx.y * 64;
    const int tq = threadIdx.x & 15, tr = threadIdx.x >> 4;
#pragma unroll
    for (int it = 0; it < 4; ++it) {
        int kl = tr + it * 16;
        int kg = k0 + kl;
        int ng = n0 + tq * 4;
        float4 v = {0.f, 0.f, 0.f, 0.f};
        if (kg < srcK) {
            const float* sp = src + (size_t)kg * srcN;
            if (ng + 3 < srcN) v = *(const float4*)(sp + ng);
            else {
                if (ng + 0 < srcN) v.x = sp[ng + 0];
                if (ng + 1 < srcN) v.y = sp[ng + 1];
                if (ng + 2 < srcN) v.z = sp[ng + 2];
                if (ng + 3 < srcN) v.w = sp[ng + 3];
            }
        }
        t[kl][tq * 4 + 0] = v.x; t[kl][tq * 4 + 1] = v.y;
        t[kl][tq * 4 + 2] = v.z; t[kl][tq * 4 + 3] = v.w;
    }
    __syncthreads();
#pragma unroll
    for (int it = 0; it < 4; ++it) {
        int nl = tr + it * 16;
        int ng = n0 + nl;
        int kg = k0 + tq * 4;
        if (ng < dstN && kg < dstK) {
            ushort4 o;
            o.x = f2bf(t[tq * 4 + 0][nl]); o.y = f2bf(t[tq * 4 + 1][nl]);
            o.z = f2bf(t[tq * 4 + 2][nl]); o.w = f2bf(t[tq * 4 + 3][nl]);
            *(ushort4*)(dst + (size_t)ng * dstK + kg) = o;
        }
    }
}

__global__ __launch_bounds__(256) void convx_kernel(
        const float* __restrict__ src, unsigned short* __restrict__ dst, int n8) {
    int idx = blockIdx.x * 256 + threadIdx.x;
    if (idx >= n8) return;
    float4 a = ((const float4*)src)[idx * 2];
    float4 b = ((const float4*)src)[idx * 2 + 1];
    uint4 o;
    o.x = (unsigned)f2bf(a.x) | ((unsigned)f2bf(a.y) << 16);
    o.y = (unsigned)f2bf(a.z) | ((unsigned)f2bf(a.w) << 16);
    o.z = (unsigned)f2bf(b.x) | ((unsigned)f2bf(b.y) << 16);
    o.w = (unsigned)f2bf(b.z) | ((unsigned)f2bf(b.w) << 16);
    ((uint4*)dst)[idx] = o;
}

__global__ __launch_bounds__(256) void zpad_kernel(unsigned short* __restrict__ attnout) {
    int idx = blockIdx.x * 256 + threadIdx.x;
    int row = idx >> 4, c = INNER + (idx & 15);
    attnout[(size_t)row * KOUTP + c] = 0;
}

__global__ __launch_bounds__(256) void adjmask_kernel(
        const float* __restrict__ adj, const int* __restrict__ rmask,
        unsigned short* __restrict__ adjbf) {
    int idx = blockIdx.x * 256 + threadIdx.x;
    int j8 = idx & 127;
    int row = idx >> 7;
    int b = row >> 10;
    int mi = rmask[row];
    const float* ap = adj + (size_t)row * NN + j8 * 8;
    const int* rm = rmask + (b << 10) + j8 * 8;
    float4 a0 = *(const float4*)ap, a1 = *(const float4*)(ap + 4);
    unsigned short o[8];
    o[0] = (mi && rm[0]) ? f2bf(a0.x) : 0;
    o[1] = (mi && rm[1]) ? f2bf(a0.y) : 0;
    o[2] = (mi && rm[2]) ? f2bf(a0.z) : 0;
    o[3] = (mi && rm[3]) ? f2bf(a0.w) : 0;
    o[4] = (mi && rm[4]) ? f2bf(a1.x) : 0;
    o[5] = (mi && rm[5]) ? f2bf(a1.y) : 0;
    o[6] = (mi && rm[6]) ? f2bf(a1.z) : 0;
    o[7] = (mi && rm[7]) ? f2bf(a1.w) : 0;
    uint4 pk;
    pk.x = (unsigned)o[0] | ((unsigned)o[1] << 16);
    pk.y = (unsigned)o[2] | ((unsigned)o[3] << 16);
    pk.z = (unsigned)o[4] | ((unsigned)o[5] << 16);
    pk.w = (unsigned)o[6] | ((unsigned)o[7] << 16);
    *(uint4*)(adjbf + (size_t)row * NN + j8 * 8) = pk;
}

// ---------------------------------------------------------------------------
// MFMA bf16 GEMM (validated R14-R17). EPI 3 scatter: Q pre-scaled by QSCL
// (0 when row masked) -> attn4 MFMA emits exp2-domain scores directly.
// ---------------------------------------------------------------------------
template<int EPI, int BM, int BN>
__global__ __launch_bounds__(256) void mm_kernel(
        const unsigned short* __restrict__ A, const unsigned short* __restrict__ W,
        const float* __restrict__ bias, void* __restrict__ Cdst,
        int K, int lda, int ldc,
        long long aBatch, long long bBatch, long long cBatch,
        unsigned short* __restrict__ Qb, unsigned short* __restrict__ Kb,
        unsigned short* __restrict__ Vtb, unsigned short* __restrict__ V2t,
        const int* __restrict__ qmask)
{
    constexpr int MF = BM / 32;
    constexpr int NF = BN / 32;
    constexpr int AROUNDS = BM / 64;
    constexpr int BROUNDS = BN / 64;
    __shared__ unsigned short As[BM * 32];
    __shared__ unsigned short Bs[BN * 32];
    const int tid = threadIdx.x;
    const int m0 = blockIdx.y * BM;
    const int n0 = blockIdx.x * BN;
    const int z  = blockIdx.z;

    const int lane = tid & 63;
    const int wv = tid >> 6;
    const int wvbase = wv << 6;
    const int wm = wv >> 1, wn = wv & 1;
    const int lrow = lane & 15, kgrp = lane >> 4;

    f32x4 acc[MF][NF];
#pragma unroll
    for (int i = 0; i < MF; ++i)
#pragma unroll
        for (int j = 0; j < NF; ++j) acc[i][j] = (f32x4){0.f, 0.f, 0.f, 0.f};

    const unsigned short* Ab = A + (size_t)z * aBatch;
    const unsigned short* Wb = W + (size_t)z * bBatch;

    for (int k0 = 0; k0 < K; k0 += 32) {
#pragma unroll
        for (int r = 0; r < AROUNDS; ++r) {
            int c = r * 256 + tid;
            const unsigned short* g = Ab + (size_t)(m0 + (c >> 2)) * lda + k0 + (c & 3) * 8;
            __builtin_amdgcn_global_load_lds((const unsigned int*)g,
                (unsigned int*)&As[(r * 256 + wvbase) * 8], 16, 0, 0);
        }
#pragma unroll
        for (int r = 0; r < BROUNDS; ++r) {
            int c = r * 256 + tid;
            const unsigned short* g = Wb + (size_t)(n0 + (c >> 2)) * K + k0 + (c & 3) * 8;
            __builtin_amdgcn_global_load_lds((const unsigned int*)g,
                (unsigned int*)&Bs[(r * 256 + wvbase) * 8], 16, 0, 0);
        }
        __syncthreads();
        short8v af[MF], bfv[NF];
#pragma unroll
        for (int f = 0; f < MF; ++f)
            af[f] = *(const short8v*)&As[(wm * (BM / 2) + f * 16 + lrow) * 32 + kgrp * 8];
#pragma unroll
        for (int f = 0; f < NF; ++f)
            bfv[f] = *(const short8v*)&Bs[(wn * (BN / 2) + f * 16 + lrow) * 32 + kgrp * 8];
#pragma unroll
        for (int fi = 0; fi < MF; ++fi)
#pragma unroll
            for (int fj = 0; fj < NF; ++fj)
                acc[fi][fj] = __builtin_amdgcn_mfma_f32_16x16x32_bf16(
                    af[fi], bfv[fj], acc[fi][fj], 0, 0, 0);
        __syncthreads();
    }

#pragma unroll
    for (int fi = 0; fi < MF; ++fi) {
#pragma unroll
        for (int fj = 0; fj < NF; ++fj) {
#pragma unroll
            for (int p = 0; p < 4; ++p) {
                int row = m0 + wm * (BM / 2) + fi * 16 + kgrp * 4 + p;
                int col = n0 + wn * (BN / 2) + fj * 16 + lrow;
                float v = acc[fi][fj][p];
                if (EPI == 0) {
                    float* C = (float*)Cdst + (size_t)z * cBatch;
                    if (bias) v += bias[col];
                    C[(size_t)row * ldc + col] = v;
                } else if (EPI == 1) {
                    unsigned short* C = (unsigned short*)Cdst;
                    C[(size_t)row * ldc + col] = f2bf(gelu_exact(v + bias[col]));
                } else if (EPI == 2) {
                    float* C = (float*)Cdst;
                    C[(size_t)row * ldc + col] += v + bias[col];
                } else {
                    if (col < QKVN) {
                        int hh  = col / 39;
                        int rem = col - hh * 39;
                        int sel = rem / 13;
                        int d   = rem - sel * 13;
                        int bb = row >> 10, n = row & (NN - 1);
                        int bh = bb * HH + hh;
                        if (sel == 0) {
                            float qs = qmask[row] ? QSCL : 0.0f;
                            Qb[((size_t)bh * NN + n) * 16 + d] = f2bf(v * qs);
                        } else if (sel == 1) {
                            int rr = (n & ~31) | (((n >> 2) & 1) << 4)
                                   | (((n >> 3) & 3) << 2) | (n & 3);
                            Kb[((size_t)bh * NN + rr) * 16 + d] = f2bf(v);
                        } else {
                            unsigned short bv = f2bf(v);
                            Vtb[((size_t)bh * 16 + d) * NN + n] = bv;
                            V2t[((size_t)bb * 256 + hh * 13 + d) * NN + n] = bv;
                        }
                    }
                }
            }
        }
    }
}

// ---------------------------------------------------------------------------
// LayerNorm (unchanged)
// ---------------------------------------------------------------------------
template<int BFOUT>
__global__ __launch_bounds__(256) void ln_kernel(
        const float* __restrict__ x, const float* __restrict__ g,
        const float* __restrict__ bta, void* __restrict__ y) {
    const int lane = threadIdx.x & 63;
    const int row = (blockIdx.x * 256 + threadIdx.x) >> 6;
    const float* xp = x + (size_t)row * DIM + lane * 8;
    float4 v0 = *(const float4*)(xp);
    float4 v1 = *(const float4*)(xp + 4);
    float s = v0.x + v0.y + v0.z + v0.w + v1.x + v1.y + v1.z + v1.w;
#pragma unroll
    for (int off = 32; off >= 1; off >>= 1) s += __shfl_xor(s, off);
    float mean = s * (1.0f / DIM);
    float q =
        (v0.x - mean) * (v0.x - mean) + (v0.y - mean) * (v0.y - mean) +
        (v0.z - mean) * (v0.z - mean) + (v0.w - mean) * (v0.w - mean) +
        (v1.x - mean) * (v1.x - mean) + (v1.y - mean) * (v1.y - mean) +
        (v1.z - mean) * (v1.z - mean) + (v1.w - mean) * (v1.w - mean);
#pragma unroll
    for (int off = 32; off >= 1; off >>= 1) q += __shfl_xor(q, off);
    float rstd = rsqrtf(q * (1.0f / DIM) + 1e-5f);
    const int c = lane * 8;
    float4 g0 = *(const float4*)(g + c), g1 = *(const float4*)(g + c + 4);
    float4 b0 = *(const float4*)(bta + c), b1 = *(const float4*)(bta + c + 4);
    float o0 = (v0.x - mean) * rstd * g0.x + b0.x;
    float o1 = (v0.y - mean) * rstd * g0.y + b0.y;
    float o2 = (v0.z - mean) * rstd * g0.z + b0.z;
    float o3 = (v0.w - mean) * rstd * g0.w + b0.w;
    float o4 = (v1.x - mean) * rstd * g1.x + b1.x;
    float o5 = (v1.y - mean) * rstd * g1.y + b1.y;
    float o6 = (v1.z - mean) * rstd * g1.z + b1.z;
    float o7 = (v1.w - mean) * rstd * g1.w + b1.w;
    if (BFOUT) {
        unsigned short* yp = (unsigned short*)y + (size_t)row * DIM + c;
        uint4 o;
        o.x = (unsigned)f2bf(o0) | ((unsigned)f2bf(o1) << 16);
        o.y = (unsigned)f2bf(o2) | ((unsigned)f2bf(o3) << 16);
        o.z = (unsigned)f2bf(o4) | ((unsigned)f2bf(o5) << 16);
        o.w = (unsigned)f2bf(o6) | ((unsigned)f2bf(o7) << 16);
        *(uint4*)yp = o;
    } else {
        float* yp = (float*)y + (size_t)row * DIM + c;
        *(float4*)(yp)     = (float4){o0, o1, o2, o3};
        *(float4*)(yp + 4) = (float4){o4, o5, o6, o7};
    }
}

// ---------------------------------------------------------------------------
// attn4 v4 (R18): Q pre-scaled (R17, kept) + uniform maskfb blend (R16 form,
// restored after R17's divergent-pointer regression) + 2-deep j-tile unroll
// for ILP (latency-bound per R17 counters: VALU 51%, MFMA 5%).
// ---------------------------------------------------------------------------
__global__ __launch_bounds__(256) void attn4_kernel(
        const unsigned short* __restrict__ Qb, const unsigned short* __restrict__ Kb,
        const unsigned short* __restrict__ Vtb, const float* __restrict__ adjout,
        const int* __restrict__ rmask, const float* __restrict__ maskfb,
        unsigned short* __restrict__ attnout) {
    const int tid = threadIdx.x;
    const int qt = blockIdx.x, h = blockIdx.y, b = blockIdx.z;
    const int bh = b * HH + h;
    const int wv = tid >> 6, lane = tid & 63;
    const int lrow = lane & 15, g = lane >> 4;
    const int q = qt * 64 + wv * 16 + lrow;
    const int mi = rmask[b * NN + q];
    const float mif = mi ? 1.0f : 0.0f;

    short8v qf = (short8v){0, 0, 0, 0, 0, 0, 0, 0};
    if (g < 2)
        qf = *(const short8v*)(Qb + ((size_t)bh * NN + q) * 16 + g * 8);

    const unsigned short* Kbh = Kb + (size_t)bh * NN * 16;
    const unsigned short* Vrow = Vtb + ((size_t)bh * 16 + lrow) * NN;
    const float* mfp = maskfb + b * NN;

    f32x4 oacc = (f32x4){0.f, 0.f, 0.f, 0.f};
    float zacc = 0.0f;

#pragma unroll 2
    for (int t = 0; t < 32; ++t) {
        const int j0 = t * 32;
        short8v kf0 = (short8v){0, 0, 0, 0, 0, 0, 0, 0};
        short8v kf1 = (short8v){0, 0, 0, 0, 0, 0, 0, 0};
        if (g < 2) {
            kf0 = *(const short8v*)(Kbh + (size_t)(j0 + lrow) * 16 + g * 8);
            kf1 = *(const short8v*)(Kbh + (size_t)(j0 + 16 + lrow) * 16 + g * 8);
        }
        f32x4 s0 = (f32x4){0.f, 0.f, 0.f, 0.f};
        f32x4 s1 = (f32x4){0.f, 0.f, 0.f, 0.f};
        s0 = __builtin_amdgcn_mfma_f32_16x16x32_bf16(kf0, qf, s0, 0, 0, 0);
        s1 = __builtin_amdgcn_mfma_f32_16x16x32_bf16(kf1, qf, s1, 0, 0, 0);
        float4 m0 = *(const float4*)&mfp[j0 + g * 8];
        float4 m1 = *(const float4*)&mfp[j0 + g * 8 + 4];
        float w0 = exp2f(fminf(s0[0], 80.f)) * fmaf(mif, m0.x - 1.f, 1.f);
        float w1 = exp2f(fminf(s0[1], 80.f)) * fmaf(mif, m0.y - 1.f, 1.f);
        float w2 = exp2f(fminf(s0[2], 80.f)) * fmaf(mif, m0.z - 1.f, 1.f);
        float w3 = exp2f(fminf(s0[3], 80.f)) * fmaf(mif, m0.w - 1.f, 1.f);
        float w4 = exp2f(fminf(s1[0], 80.f)) * fmaf(mif, m1.x - 1.f, 1.f);
        float w5 = exp2f(fminf(s1[1], 80.f)) * fmaf(mif, m1.y - 1.f, 1.f);
        float w6 = exp2f(fminf(s1[2], 80.f)) * fmaf(mif, m1.z - 1.f, 1.f);
        float w7 = exp2f(fminf(s1[3], 80.f)) * fmaf(mif, m1.w - 1.f, 1.f);
        zacc += ((w0 + w1) + (w2 + w3)) + ((w4 + w5) + (w6 + w7));
        unsigned p01, p23, p45, p67;
        asm("v_cvt_pk_bf16_f32 %0, %1, %2" : "=v"(p01) : "v"(w0), "v"(w1));
        asm("v_cvt_pk_bf16_f32 %0, %1, %2" : "=v"(p23) : "v"(w2), "v"(w3));
        asm("v_cvt_pk_bf16_f32 %0, %1, %2" : "=v"(p45) : "v"(w4), "v"(w5));
        asm("v_cvt_pk_bf16_f32 %0, %1, %2" : "=v"(p67) : "v"(w6), "v"(w7));
        union { uint4 u4; short8v s8; } pu;
        pu.u4 = (uint4){p01, p23, p45, p67};
        short8v vf = *(const short8v*)(Vrow + j0 + g * 8);
        oacc = __builtin_amdgcn_mfma_f32_16x16x32_bf16(vf, pu.s8, oacc, 0, 0, 0);
    }

    zacc += __shfl_xor(zacc, 16);
    zacc += __shfl_xor(zacc, 32);
    float inv = 1.0f / zacc;

    const float* arow = adjout + ((size_t)(b * NN + q)) * 256 + h * 13;
    unsigned short* orow = attnout + (size_t)(b * NN + q) * KOUTP + h * 13;
#pragma unroll
    for (int p = 0; p < 4; ++p) {
        int d = 4 * g + p;
        if (d < 13)
            orow[d] = f2bf(fmaf(oacc[p], inv, 0.5f * arow[d]));
    }
}

// ---------------------------------------------------------------------------
// Coalesced pool (unchanged)
// ---------------------------------------------------------------------------
__global__ __launch_bounds__(256) void pool1_kernel(
        const float* __restrict__ xn, float* __restrict__ poolpart) {
    __shared__ float red[256][4];
    const int ch = blockIdx.x, b = blockIdx.y;
    const int c4 = threadIdx.x & 127, p = threadIdx.x >> 7;
    const float* base = xn + ((size_t)(b * NN) + ch * 64 + p) * DIM + c4 * 4;
    float4 s = {0.f, 0.f, 0.f, 0.f};
    for (int r = 0; r < 32; ++r) {
        float4 v = *(const float4*)(base + (size_t)r * 2 * DIM);
        s.x += v.x; s.y += v.y; s.z += v.z; s.w += v.w;
    }
    *(float4*)red[threadIdx.x] = s;
    __syncthreads();
    if (threadIdx.x < 128) {
        float4 a = *(float4*)red[threadIdx.x];
        float4 c = *(float4*)red[threadIdx.x + 128];
        float4 o = {a.x + c.x, a.y + c.y, a.z + c.z, a.w + c.w};
        *(float4*)(poolpart + (size_t)(b * 16 + ch) * DIM + c4 * 4) = o;
    }
}

__global__ __launch_bounds__(256) void pool2_kernel(
        const float* __restrict__ poolpart, float* __restrict__ pooled) {
    int c = blockIdx.x * 256 + threadIdx.x;
    int b = c >> 9, col = c & 511;
    float s = 0.f;
    for (int ch = 0; ch < 16; ++ch)
        s += poolpart[(size_t)(b * 16 + ch) * DIM + col];
    pooled[c] = s * (1.0f / NN);
}

// ---------------------------------------------------------------------------
// Final MLP split-K (validated R9)
// ---------------------------------------------------------------------------
__global__ __launch_bounds__(256) void ffo1a_kernel(
        const float* __restrict__ pooled, const float* __restrict__ w,
        float* __restrict__ part) {
    int n = blockIdx.x * 256 + threadIdx.x;
    int kc = blockIdx.y;
    float s0 = 0.f, s1 = 0.f, s2 = 0.f, s3 = 0.f;
    for (int k = kc * 128; k < kc * 128 + 128; ++k) {
        float wv = w[(size_t)k * FFH + n];
        s0 = fmaf(pooled[k], wv, s0);
        s1 = fmaf(pooled[512 + k], wv, s1);
        s2 = fmaf(pooled[1024 + k], wv, s2);
        s3 = fmaf(pooled[1536 + k], wv, s3);
    }
    part[(size_t)(kc * 4 + 0) * FFH + n] = s0;
    part[(size_t)(kc * 4 + 1) * FFH + n] = s1;
    part[(size_t)(kc * 4 + 2) * FFH + n] = s2;
    part[(size_t)(kc * 4 + 3) * FFH + n] = s3;
}

__global__ __launch_bounds__(256) void ffo1b_kernel(
        const float* __restrict__ part, const float* __restrict__ bias,
        float* __restrict__ ffoh) {
    int c = blockIdx.x * 256 + threadIdx.x;
    int b = c >> 11, n = c & 2047;
    float s = bias[n];
#pragma unroll
    for (int kc = 0; kc < 4; ++kc)
        s += part[(size_t)(kc * 4 + b) * FFH + n];
    ffoh[c] = gelu_exact(s);
}

__global__ __launch_bounds__(256) void ffo2a_kernel(
        const float* __restrict__ ffoh, const float* __restrict__ w,
        float* __restrict__ part) {
    int n = blockIdx.x * 256 + threadIdx.x;
    int kc = blockIdx.y;
    float s0 = 0.f, s1 = 0.f, s2 = 0.f, s3 = 0.f;
    for (int k = kc * 128; k < kc * 128 + 128; ++k) {
        float wv = w[(size_t)k * DIM + n];
        s0 = fmaf(ffoh[k], wv, s0);
        s1 = fmaf(ffoh[2048 + k], wv, s1);
        s2 = fmaf(ffoh[4096 + k], wv, s2);
        s3 = fmaf(ffoh[6144 + k], wv, s3);
    }
    part[(size_t)(kc * 4 + 0) * DIM + n] = s0;
    part[(size_t)(kc * 4 + 1) * DIM + n] = s1;
    part[(size_t)(kc * 4 + 2) * DIM + n] = s2;
    part[(size_t)(kc * 4 + 3) * DIM + n] = s3;
}

__global__ __launch_bounds__(256) void ffo2b_kernel(
        const float* __restrict__ part, const float* __restrict__ bias,
        float* __restrict__ out) {
    int c = blockIdx.x * 256 + threadIdx.x;
    int b = c >> 9, n = c & 511;
    float s = bias[n];
#pragma unroll
    for (int kc = 0; kc < 16; ++kc)
        s += part[(size_t)(kc * 4 + b) * DIM + n];
    out[c] = s;
}

// ---------------------------------------------------------------------------
// Launch. 256 MiB ws proven (R15); no-alias layout (R16), ~71.7 MB high-water.
// ---------------------------------------------------------------------------
extern "C" void kernel_launch(void* const* d_in, const int* in_sizes, int n_in,
                              void* d_out, int out_size, void* d_ws, size_t ws_size,
                              hipStream_t stream) {
    const float* x       = (const float*)d_in[0];
    const void*  mraw    = d_in[1];
    const float* adj     = (const float*)d_in[2];
    const float* embed_w = (const float*)d_in[3];
    const float* embed_b = (const float*)d_in[4];
    const float* ln1_g   = (const float*)d_in[5];
    const float* ln1_b   = (const float*)d_in[6];
    const float* qkv_w   = (const float*)d_in[7];
    const float* out_w   = (const float*)d_in[8];
    const float* out_b   = (const float*)d_in[9];
    const float* ln2_g   = (const float*)d_in[10];
    const float* ln2_b   = (const float*)d_in[11];
    const float* ff1_w   = (const float*)d_in[12];
    const float* ff1_b   = (const float*)d_in[13];
    const float* ff2_w   = (const float*)d_in[14];
    const float* ff2_b   = (const float*)d_in[15];
    const float* lnout_g = (const float*)d_in[16];
    const float* lnout_b = (const float*)d_in[17];
    const float* ffo1_w  = (const float*)d_in[18];
    const float* ffo1_b  = (const float*)d_in[19];
    const float* ffo2_w  = (const float*)d_in[20];
    const float* ffo2_b  = (const float*)d_in[21];

    char* ws = (char*)d_ws;
    float*          h       = (float*)(ws + 0);
    unsigned short* xnbf    = (unsigned short*)(ws + 8388608);
    unsigned short* adjbf   = (unsigned short*)(ws + 12582912);
    unsigned short* Qb      = (unsigned short*)(ws + 20971520);
    unsigned short* Kb      = (unsigned short*)(ws + 23068672);
    unsigned short* Vtb     = (unsigned short*)(ws + 25165824);
    unsigned short* V2t     = (unsigned short*)(ws + 27262976);
    float*          adjout  = (float*)(ws + 29360128);
    unsigned short* ffh     = (unsigned short*)(ws + 33554432);
    float*          xnf     = (float*)(ws + 50331648);
    unsigned short* attnout = (unsigned short*)(ws + 58720256);
    unsigned short* embedwt = (unsigned short*)(ws + 60555264);
    unsigned short* qkvwt   = (unsigned short*)(ws + 61079552);
    unsigned short* outwt   = (unsigned short*)(ws + 62390272);
    unsigned short* ff1wt   = (unsigned short*)(ws + 62849024);
    unsigned short* ff2wt   = (unsigned short*)(ws + 67043328);
    float*          poolpart= (float*)(ws + 71237632);
    float*          pooled  = (float*)(ws + 71368704);
    float*          ffoh    = (float*)(ws + 71376896);
    float*          part1   = (float*)(ws + 71409664);
    float*          part2   = (float*)(ws + 71540736);
    int*            rowmask = (int*)(ws + 71671808);
    float*          maskfb  = (float*)(ws + 71688192);
    int*            flag    = (int*)(ws + 71704576);

    mask_detect_kernel<<<1, 1024, 0, stream>>>((const unsigned char*)mraw, flag);
    mask_convert_kernel<<<16, 256, 0, stream>>>(mraw, flag, rowmask, maskfb);
    convx_kernel<<<1024, 256, 0, stream>>>(x, xnbf, ROWS * DIM / 8);
    convw_kernel<<<dim3(8, 8), 256, 0, stream>>>(embed_w, embedwt, 512, 512, 512, 512);
    for (int l = 0; l < 2; ++l) {
        convw_kernel<<<dim3(10, 8), 256, 0, stream>>>(qkv_w + (size_t)l * 512 * 624,
            qkvwt + (size_t)l * QKVNP * 512, 512, 624, 512, QKVNP);
        convw_kernel<<<dim3(8, 4), 256, 0, stream>>>(out_w + (size_t)l * 208 * 512,
            outwt + (size_t)l * 512 * KOUTP, 208, 512, KOUTP, 512);
        convw_kernel<<<dim3(32, 8), 256, 0, stream>>>(ff1_w + (size_t)l * 512 * 2048,
            ff1wt + (size_t)l * 2048 * 512, 512, 2048, 512, 2048);
        convw_kernel<<<dim3(8, 32), 256, 0, stream>>>(ff2_w + (size_t)l * 512 * 2048,
            ff2wt + (size_t)l * 512 * 2048, 2048, 512, 2048, 512);
    }
    zpad_kernel<<<256, 256, 0, stream>>>(attnout);
    padzero_kernel<<<704, 256, 0, stream>>>(Qb, Kb, Vtb, V2t);
    adjmask_kernel<<<2048, 256, 0, stream>>>(adj, rowmask, adjbf);

    mm_kernel<0, 64, 64><<<dim3(8, 64, 1), 256, 0, stream>>>(
        xnbf, embedwt, embed_b, h, 512, 512, 512, 0, 0, 0,
        nullptr, nullptr, nullptr, nullptr, nullptr);

    for (int l = 0; l < 2; ++l) {
        ln_kernel<1><<<1024, 256, 0, stream>>>(h, ln1_g + l * DIM, ln1_b + l * DIM, xnbf);
        mm_kernel<3, 64, 64><<<dim3(10, 64, 1), 256, 0, stream>>>(
            xnbf, qkvwt + (size_t)l * QKVNP * 512, nullptr, nullptr,
            512, 512, 0, 0, 0, 0, Qb, Kb, Vtb, V2t, rowmask);
        mm_kernel<0, 64, 64><<<dim3(4, 16, 4), 256, 0, stream>>>(
            adjbf, V2t, nullptr, adjout, 1024, 1024, 256,
            (long long)NN * NN, (long long)256 * NN, (long long)NN * 256,
            nullptr, nullptr, nullptr, nullptr, nullptr);
        attn4_kernel<<<dim3(16, 16, 4), 256, 0, stream>>>(
            Qb, Kb, Vtb, adjout, rowmask, maskfb, attnout);
        mm_kernel<2, 64, 64><<<dim3(8, 64, 1), 256, 0, stream>>>(
            attnout, outwt + (size_t)l * 512 * KOUTP, out_b + l * DIM, h,
            KOUTP, KOUTP, 512, 0, 0, 0, nullptr, nullptr, nullptr, nullptr, nullptr);
        ln_kernel<1><<<1024, 256, 0, stream>>>(h, ln2_g + l * DIM, ln2_b + l * DIM, xnbf);
        mm_kernel<1, 128, 128><<<dim3(16, 32, 1), 256, 0, stream>>>(
            xnbf, ff1wt + (size_t)l * 2048 * 512, ff1_b + l * FFH, ffh,
            512, 512, 2048, 0, 0, 0, nullptr, nullptr, nullptr, nullptr, nullptr);
        mm_kernel<2, 64, 64><<<dim3(8, 64, 1), 256, 0, stream>>>(
            ffh, ff2wt + (size_t)l * 512 * 2048, ff2_b + l * DIM, h,
            2048, 2048, 512, 0, 0, 0, nullptr, nullptr, nullptr, nullptr, nullptr);
    }

    ln_kernel<0><<<1024, 256, 0, stream>>>(h, lnout_g, lnout_b, xnf);
    pool1_kernel<<<dim3(16, 4), 256, 0, stream>>>(xnf, poolpart);
    pool2_kernel<<<8, 256, 0, stream>>>(poolpart, pooled);
    ffo1a_kernel<<<dim3(8, 4), 256, 0, stream>>>(pooled, ffo1_w, part1);
    ffo1b_kernel<<<32, 256, 0, stream>>>(part1, ffo1_b, ffoh);
    ffo2a_kernel<<<dim3(2, 16), 256, 0, stream>>>(ffoh, ffo2_w, part2);
    ffo2b_kernel<<<8, 256, 0, stream>>>(part2, ffo2_b, (float*)d_out);
}

// Round 19
// 369.624 us; speedup vs baseline: 1.0569x; 1.0329x over previous
//
#include <hip/hip_runtime.h>
#include <math.h>

#define BB    4
#define NN    1024
#define DIM   512
#define HH    16
#define DH    13
#define INNER 208
#define QKVN  624
#define QKVNP 640
#define KOUTP 224
#define FFH   2048
#define ROWS  4096

typedef __attribute__((ext_vector_type(8))) short short8v;
typedef __attribute__((ext_vector_type(4))) float f32x4;

// softmax scale * log2(e), baked into Q at scatter time (R17, validated)
#define QSCL (0.27735009811261457f * 1.4426950408889634f)

__device__ __forceinline__ unsigned short f2bf(float f) {
    union { float f; unsigned int u; } x; x.f = f;
    unsigned int u = x.u + 0x7FFFu + ((x.u >> 16) & 1u);
    return (unsigned short)(u >> 16);
}
__device__ __forceinline__ float gelu_exact(float x) {
    return 0.5f * x * (1.0f + erff(x * 0.70710678118654752f));
}

// ---------------------------------------------------------------------------
// Mask normalization (validated R4+)
// ---------------------------------------------------------------------------
__global__ __launch_bounds__(1024) void mask_detect_kernel(
        const unsigned char* __restrict__ mraw, int* __restrict__ flag) {
    __shared__ int any;
    if (threadIdx.x == 0) any = 0;
    __syncthreads();
    int t = threadIdx.x;
    int v = mraw[4 * t + 1] | mraw[4 * t + 2] | mraw[4 * t + 3];
    if (v) atomicOr(&any, 1);
    __syncthreads();
    if (threadIdx.x == 0) *flag = any;
}

__global__ __launch_bounds__(256) void mask_convert_kernel(
        const void* __restrict__ mraw, const int* __restrict__ flag,
        int* __restrict__ rowmask) {
    int i = blockIdx.x * 256 + threadIdx.x;
    int v;
    if (*flag) v = ((const unsigned char*)mraw)[i] != 0;
    else       v = ((const int*)mraw)[i] != 0;
    rowmask[i] = v;
}

// ---------------------------------------------------------------------------
// One-time pad setup (R19): mask folded into the QK contraction lanes.
//  Qb[bh][n][13] = mi ? 1.0 : 0.0   (bf16)   [d14,d15 = 0]
//  Kb[bh][rr(n)][13] = mj ? 0 : -128 (bf16)  [d14,d15 = 0]
//  => MFMA dot = s - 128*(mi && !mj); exp2 -> ~0 for masked cols;
//     !mi rows have Q==0 entirely -> s=0 -> w=1 uniform (reference semantics).
// Vtb pad rows d=13..15 and V2t pad rows 208..255 zeroed (hygiene).
// qkv scatter writes only d<13, so these lanes persist across layers.
// ---------------------------------------------------------------------------
__global__ __launch_bounds__(256) void padzero_kernel(
        unsigned short* __restrict__ Qb, unsigned short* __restrict__ Kb,
        unsigned short* __restrict__ Vtb, unsigned short* __restrict__ V2t,
        const int* __restrict__ rmask) {
    int idx = blockIdx.x * 256 + threadIdx.x;
    if (idx < 65536) {
        // Qb row idx = bh*1024 + n ; b = bh>>4
        int bh = idx >> 10, n = idx & 1023;
        int mi = rmask[(bh >> 4) * NN + n];
        unsigned short* p = Qb + (size_t)idx * 16 + 13;
        p[0] = mi ? f2bf(1.0f) : (unsigned short)0;
        p[1] = 0; p[2] = 0;
    } else if (idx < 131072) {
        int i = idx - 65536;                  // original n-index
        int bh = i >> 10, n = i & 1023;
        int mj = rmask[(bh >> 4) * NN + n];
        int rr = (n & ~31) | (((n >> 2) & 1) << 4)
               | (((n >> 3) & 3) << 2) | (n & 3);
        unsigned short* p = Kb + ((size_t)bh * NN + rr) * 16 + 13;
        p[0] = mj ? (unsigned short)0 : f2bf(-128.0f);
        p[1] = 0; p[2] = 0;
    } else if (idx < 155648) {
        int i = idx - 131072;
        int bh = i / 384, r = (i >> 7) % 3, c = i & 127;
        *(uint4*)(Vtb + ((size_t)(bh * 16 + 13 + r) * 1024 + c * 8)) =
            (uint4){0u, 0u, 0u, 0u};
    } else if (idx < 180224) {
        int i = idx - 155648;
        int b = i / 6144, r = (i >> 7) % 48, c = i & 127;
        *(uint4*)(V2t + ((size_t)(b * 256 + 208 + r) * 1024 + c * 8)) =
            (uint4){0u, 0u, 0u, 0u};
    }
}

// ---------------------------------------------------------------------------
// Weight transpose-convert (validated R7+)
// ---------------------------------------------------------------------------
__global__ __launch_bounds__(256) void convw_kernel(
        const float* __restrict__ src, unsigned short* __restrict__ dst,
        int srcK, int srcN, int dstK, int dstN) {
    __shared__ float t[64][65];
    const int n0 = blockIdx.x * 64, k0 = blockIdx.y * 64;
    const int tq = threadIdx.x & 15, tr = threadIdx.x >> 4;
#pragma unroll
    for (int it = 0; it < 4; ++it) {
        int kl = tr + it * 16;
        int kg = k0 + kl;
        int ng = n0 + tq * 4;
        float4 v = {0.f, 0.f, 0.f, 0.f};
        if (kg < srcK) {
            const float* sp = src + (size_t)kg * srcN;
            if (ng + 3 < srcN) v = *(const float4*)(sp + ng);
            else {
                if (ng + 0 < srcN) v.x = sp[ng + 0];
                if (ng + 1 < srcN) v.y = sp[ng + 1];
                if (ng + 2 < srcN) v.z = sp[ng + 2];
                if (ng + 3 < srcN) v.w = sp[ng + 3];
            }
        }
        t[kl][tq * 4 + 0] = v.x; t[kl][tq * 4 + 1] = v.y;
        t[kl][tq * 4 + 2] = v.z; t[kl][tq * 4 + 3] = v.w;
    }
    __syncthreads();
#pragma unroll
    for (int it = 0; it < 4; ++it) {
        int nl = tr + it * 16;
        int ng = n0 + nl;
        int kg = k0 + tq * 4;
        if (ng < dstN && kg < dstK) {
            ushort4 o;
            o.x = f2bf(t[tq * 4 + 0][nl]); o.y = f2bf(t[tq * 4 + 1][nl]);
            o.z = f2bf(t[tq * 4 + 2][nl]); o.w = f2bf(t[tq * 4 + 3][nl]);
            *(ushort4*)(dst + (size_t)ng * dstK + kg) = o;
        }
    }
}

__global__ __launch_bounds__(256) void convx_kernel(
        const float* __restrict__ src, unsigned short* __restrict__ dst, int n8) {
    int idx = blockIdx.x * 256 + threadIdx.x;
    if (idx >= n8) return;
    float4 a = ((const float4*)src)[idx * 2];
    float4 b = ((const float4*)src)[idx * 2 + 1];
    uint4 o;
    o.x = (unsigned)f2bf(a.x) | ((unsigned)f2bf(a.y) << 16);
    o.y = (unsigned)f2bf(a.z) | ((unsigned)f2bf(a.w) << 16);
    o.z = (unsigned)f2bf(b.x) | ((unsigned)f2bf(b.y) << 16);
    o.w = (unsigned)f2bf(b.z) | ((unsigned)f2bf(b.w) << 16);
    ((uint4*)dst)[idx] = o;
}

__global__ __launch_bounds__(256) void zpad_kernel(unsigned short* __restrict__ attnout) {
    int idx = blockIdx.x * 256 + threadIdx.x;
    int row = idx >> 4, c = INNER + (idx & 15);
    attnout[(size_t)row * KOUTP + c] = 0;
}

__global__ __launch_bounds__(256) void adjmask_kernel(
        const float* __restrict__ adj, const int* __restrict__ rmask,
        unsigned short* __restrict__ adjbf) {
    int idx = blockIdx.x * 256 + threadIdx.x;
    int j8 = idx & 127;
    int row = idx >> 7;
    int b = row >> 10;
    int mi = rmask[row];
    const float* ap = adj + (size_t)row * NN + j8 * 8;
    const int* rm = rmask + (b << 10) + j8 * 8;
    float4 a0 = *(const float4*)ap, a1 = *(const float4*)(ap + 4);
    unsigned short o[8];
    o[0] = (mi && rm[0]) ? f2bf(a0.x) : 0;
    o[1] = (mi && rm[1]) ? f2bf(a0.y) : 0;
    o[2] = (mi && rm[2]) ? f2bf(a0.z) : 0;
    o[3] = (mi && rm[3]) ? f2bf(a0.w) : 0;
    o[4] = (mi && rm[4]) ? f2bf(a1.x) : 0;
    o[5] = (mi && rm[5]) ? f2bf(a1.y) : 0;
    o[6] = (mi && rm[6]) ? f2bf(a1.z) : 0;
    o[7] = (mi && rm[7]) ? f2bf(a1.w) : 0;
    uint4 pk;
    pk.x = (unsigned)o[0] | ((unsigned)o[1] << 16);
    pk.y = (unsigned)o[2] | ((unsigned)o[3] << 16);
    pk.z = (unsigned)o[4] | ((unsigned)o[5] << 16);
    pk.w = (unsigned)o[6] | ((unsigned)o[7] << 16);
    *(uint4*)(adjbf + (size_t)row * NN + j8 * 8) = pk;
}

// ---------------------------------------------------------------------------
// MFMA bf16 GEMM (validated R14-R18). EPI 3 scatter: Q pre-scaled by QSCL
// (0 when row masked); writes only d<13 so R19 mask lanes persist.
// ---------------------------------------------------------------------------
template<int EPI, int BM, int BN>
__global__ __launch_bounds__(256) void mm_kernel(
        const unsigned short* __restrict__ A, const unsigned short* __restrict__ W,
        const float* __restrict__ bias, void* __restrict__ Cdst,
        int K, int lda, int ldc,
        long long aBatch, long long bBatch, long long cBatch,
        unsigned short* __restrict__ Qb, unsigned short* __restrict__ Kb,
        unsigned short* __restrict__ Vtb, unsigned short* __restrict__ V2t,
        const int* __restrict__ qmask)
{
    constexpr int MF = BM / 32;
    constexpr int NF = BN / 32;
    constexpr int AROUNDS = BM / 64;
    constexpr int BROUNDS = BN / 64;
    __shared__ unsigned short As[BM * 32];
    __shared__ unsigned short Bs[BN * 32];
    const int tid = threadIdx.x;
    const int m0 = blockIdx.y * BM;
    const int n0 = blockIdx.x * BN;
    const int z  = blockIdx.z;

    const int lane = tid & 63;
    const int wv = tid >> 6;
    const int wvbase = wv << 6;
    const int wm = wv >> 1, wn = wv & 1;
    const int lrow = lane & 15, kgrp = lane >> 4;

    f32x4 acc[MF][NF];
#pragma unroll
    for (int i = 0; i < MF; ++i)
#pragma unroll
        for (int j = 0; j < NF; ++j) acc[i][j] = (f32x4){0.f, 0.f, 0.f, 0.f};

    const unsigned short* Ab = A + (size_t)z * aBatch;
    const unsigned short* Wb = W + (size_t)z * bBatch;

    for (int k0 = 0; k0 < K; k0 += 32) {
#pragma unroll
        for (int r = 0; r < AROUNDS; ++r) {
            int c = r * 256 + tid;
            const unsigned short* g = Ab + (size_t)(m0 + (c >> 2)) * lda + k0 + (c & 3) * 8;
            __builtin_amdgcn_global_load_lds((const unsigned int*)g,
                (unsigned int*)&As[(r * 256 + wvbase) * 8], 16, 0, 0);
        }
#pragma unroll
        for (int r = 0; r < BROUNDS; ++r) {
            int c = r * 256 + tid;
            const unsigned short* g = Wb + (size_t)(n0 + (c >> 2)) * K + k0 + (c & 3) * 8;
            __builtin_amdgcn_global_load_lds((const unsigned int*)g,
                (unsigned int*)&Bs[(r * 256 + wvbase) * 8], 16, 0, 0);
        }
        __syncthreads();
        short8v af[MF], bfv[NF];
#pragma unroll
        for (int f = 0; f < MF; ++f)
            af[f] = *(const short8v*)&As[(wm * (BM / 2) + f * 16 + lrow) * 32 + kgrp * 8];
#pragma unroll
        for (int f = 0; f < NF; ++f)
            bfv[f] = *(const short8v*)&Bs[(wn * (BN / 2) + f * 16 + lrow) * 32 + kgrp * 8];
#pragma unroll
        for (int fi = 0; fi < MF; ++fi)
#pragma unroll
            for (int fj = 0; fj < NF; ++fj)
                acc[fi][fj] = __builtin_amdgcn_mfma_f32_16x16x32_bf16(
                    af[fi], bfv[fj], acc[fi][fj], 0, 0, 0);
        __syncthreads();
    }

#pragma unroll
    for (int fi = 0; fi < MF; ++fi) {
#pragma unroll
        for (int fj = 0; fj < NF; ++fj) {
#pragma unroll
            for (int p = 0; p < 4; ++p) {
                int row = m0 + wm * (BM / 2) + fi * 16 + kgrp * 4 + p;
                int col = n0 + wn * (BN / 2) + fj * 16 + lrow;
                float v = acc[fi][fj][p];
                if (EPI == 0) {
                    float* C = (float*)Cdst + (size_t)z * cBatch;
                    if (bias) v += bias[col];
                    C[(size_t)row * ldc + col] = v;
                } else if (EPI == 1) {
                    unsigned short* C = (unsigned short*)Cdst;
                    C[(size_t)row * ldc + col] = f2bf(gelu_exact(v + bias[col]));
                } else if (EPI == 2) {
                    float* C = (float*)Cdst;
                    C[(size_t)row * ldc + col] += v + bias[col];
                } else {
                    if (col < QKVN) {
                        int hh  = col / 39;
                        int rem = col - hh * 39;
                        int sel = rem / 13;
                        int d   = rem - sel * 13;
                        int bb = row >> 10, n = row & (NN - 1);
                        int bh = bb * HH + hh;
                        if (sel == 0) {
                            float qs = qmask[row] ? QSCL : 0.0f;
                            Qb[((size_t)bh * NN + n) * 16 + d] = f2bf(v * qs);
                        } else if (sel == 1) {
                            int rr = (n & ~31) | (((n >> 2) & 1) << 4)
                                   | (((n >> 3) & 3) << 2) | (n & 3);
                            Kb[((size_t)bh * NN + rr) * 16 + d] = f2bf(v);
                        } else {
                            unsigned short bv = f2bf(v);
                            Vtb[((size_t)bh * 16 + d) * NN + n] = bv;
                            V2t[((size_t)bb * 256 + hh * 13 + d) * NN + n] = bv;
                        }
                    }
                }
            }
        }
    }
}

// ---------------------------------------------------------------------------
// LayerNorm (unchanged)
// ---------------------------------------------------------------------------
template<int BFOUT>
__global__ __launch_bounds__(256) void ln_kernel(
        const float* __restrict__ x, const float* __restrict__ g,
        const float* __restrict__ bta, void* __restrict__ y) {
    const int lane = threadIdx.x & 63;
    const int row = (blockIdx.x * 256 + threadIdx.x) >> 6;
    const float* xp = x + (size_t)row * DIM + lane * 8;
    float4 v0 = *(const float4*)(xp);
    float4 v1 = *(const float4*)(xp + 4);
    float s = v0.x + v0.y + v0.z + v0.w + v1.x + v1.y + v1.z + v1.w;
#pragma unroll
    for (int off = 32; off >= 1; off >>= 1) s += __shfl_xor(s, off);
    float mean = s * (1.0f / DIM);
    float q =
        (v0.x - mean) * (v0.x - mean) + (v0.y - mean) * (v0.y - mean) +
        (v0.z - mean) * (v0.z - mean) + (v0.w - mean) * (v0.w - mean) +
        (v1.x - mean) * (v1.x - mean) + (v1.y - mean) * (v1.y - mean) +
        (v1.z - mean) * (v1.z - mean) + (v1.w - mean) * (v1.w - mean);
#pragma unroll
    for (int off = 32; off >= 1; off >>= 1) q += __shfl_xor(q, off);
    float rstd = rsqrtf(q * (1.0f / DIM) + 1e-5f);
    const int c = lane * 8;
    float4 g0 = *(const float4*)(g + c), g1 = *(const float4*)(g + c + 4);
    float4 b0 = *(const float4*)(bta + c), b1 = *(const float4*)(bta + c + 4);
    float o0 = (v0.x - mean) * rstd * g0.x + b0.x;
    float o1 = (v0.y - mean) * rstd * g0.y + b0.y;
    float o2 = (v0.z - mean) * rstd * g0.z + b0.z;
    float o3 = (v0.w - mean) * rstd * g0.w + b0.w;
    float o4 = (v1.x - mean) * rstd * g1.x + b1.x;
    float o5 = (v1.y - mean) * rstd * g1.y + b1.y;
    float o6 = (v1.z - mean) * rstd * g1.z + b1.z;
    float o7 = (v1.w - mean) * rstd * g1.w + b1.w;
    if (BFOUT) {
        unsigned short* yp = (unsigned short*)y + (size_t)row * DIM + c;
        uint4 o;
        o.x = (unsigned)f2bf(o0) | ((unsigned)f2bf(o1) << 16);
        o.y = (unsigned)f2bf(o2) | ((unsigned)f2bf(o3) << 16);
        o.z = (unsigned)f2bf(o4) | ((unsigned)f2bf(o5) << 16);
        o.w = (unsigned)f2bf(o6) | ((unsigned)f2bf(o7) << 16);
        *(uint4*)yp = o;
    } else {
        float* yp = (float*)y + (size_t)row * DIM + c;
        *(float4*)(yp)     = (float4){o0, o1, o2, o3};
        *(float4*)(yp + 4) = (float4){o4, o5, o6, o7};
    }
}

// ---------------------------------------------------------------------------
// attn4 v5 (R19): mask fully folded into QK contraction (d=13 lanes).
// Inner loop: 3 MFMA + 8 exp2 + 8 fminf + adds + 4 cvt_pk. No mask loads,
// no blends, no divergence.
// ---------------------------------------------------------------------------
__global__ __launch_bounds__(256) void attn4_kernel(
        const unsigned short* __restrict__ Qb, const unsigned short* __restrict__ Kb,
        const unsigned short* __restrict__ Vtb, const float* __restrict__ adjout,
        unsigned short* __restrict__ attnout) {
    const int tid = threadIdx.x;
    const int qt = blockIdx.x, h = blockIdx.y, b = blockIdx.z;
    const int bh = b * HH + h;
    const int wv = tid >> 6, lane = tid & 63;
    const int lrow = lane & 15, g = lane >> 4;
    const int q = qt * 64 + wv * 16 + lrow;

    short8v qf = (short8v){0, 0, 0, 0, 0, 0, 0, 0};
    if (g < 2)
        qf = *(const short8v*)(Qb + ((size_t)bh * NN + q) * 16 + g * 8);

    const unsigned short* Kbh = Kb + (size_t)bh * NN * 16;
    const unsigned short* Vrow = Vtb + ((size_t)bh * 16 + lrow) * NN;

    f32x4 oacc = (f32x4){0.f, 0.f, 0.f, 0.f};
    float zacc = 0.0f;

#pragma unroll 2
    for (int t = 0; t < 32; ++t) {
        const int j0 = t * 32;
        short8v kf0 = (short8v){0, 0, 0, 0, 0, 0, 0, 0};
        short8v kf1 = (short8v){0, 0, 0, 0, 0, 0, 0, 0};
        if (g < 2) {
            kf0 = *(const short8v*)(Kbh + (size_t)(j0 + lrow) * 16 + g * 8);
            kf1 = *(const short8v*)(Kbh + (size_t)(j0 + 16 + lrow) * 16 + g * 8);
        }
        f32x4 s0 = (f32x4){0.f, 0.f, 0.f, 0.f};
        f32x4 s1 = (f32x4){0.f, 0.f, 0.f, 0.f};
        s0 = __builtin_amdgcn_mfma_f32_16x16x32_bf16(kf0, qf, s0, 0, 0, 0);
        s1 = __builtin_amdgcn_mfma_f32_16x16x32_bf16(kf1, qf, s1, 0, 0, 0);
        float w0 = exp2f(fminf(s0[0], 80.f));
        float w1 = exp2f(fminf(s0[1], 80.f));
        float w2 = exp2f(fminf(s0[2], 80.f));
        float w3 = exp2f(fminf(s0[3], 80.f));
        float w4 = exp2f(fminf(s1[0], 80.f));
        float w5 = exp2f(fminf(s1[1], 80.f));
        float w6 = exp2f(fminf(s1[2], 80.f));
        float w7 = exp2f(fminf(s1[3], 80.f));
        zacc += ((w0 + w1) + (w2 + w3)) + ((w4 + w5) + (w6 + w7));
        unsigned p01, p23, p45, p67;
        asm("v_cvt_pk_bf16_f32 %0, %1, %2" : "=v"(p01) : "v"(w0), "v"(w1));
        asm("v_cvt_pk_bf16_f32 %0, %1, %2" : "=v"(p23) : "v"(w2), "v"(w3));
        asm("v_cvt_pk_bf16_f32 %0, %1, %2" : "=v"(p45) : "v"(w4), "v"(w5));
        asm("v_cvt_pk_bf16_f32 %0, %1, %2" : "=v"(p67) : "v"(w6), "v"(w7));
        union { uint4 u4; short8v s8; } pu;
        pu.u4 = (uint4){p01, p23, p45, p67};
        short8v vf = *(const short8v*)(Vrow + j0 + g * 8);
        oacc = __builtin_amdgcn_mfma_f32_16x16x32_bf16(vf, pu.s8, oacc, 0, 0, 0);
    }

    zacc += __shfl_xor(zacc, 16);
    zacc += __shfl_xor(zacc, 32);
    float inv = 1.0f / zacc;

    const float* arow = adjout + ((size_t)(b * NN + q)) * 256 + h * 13;
    unsigned short* orow = attnout + (size_t)(b * NN + q) * KOUTP + h * 13;
#pragma unroll
    for (int p = 0; p < 4; ++p) {
        int d = 4 * g + p;
        if (d < 13)
            orow[d] = f2bf(fmaf(oacc[p], inv, 0.5f * arow[d]));
    }
}

// ---------------------------------------------------------------------------
// Coalesced pool (unchanged)
// ---------------------------------------------------------------------------
__global__ __launch_bounds__(256) void pool1_kernel(
        const float* __restrict__ xn, float* __restrict__ poolpart) {
    __shared__ float red[256][4];
    const int ch = blockIdx.x, b = blockIdx.y;
    const int c4 = threadIdx.x & 127, p = threadIdx.x >> 7;
    const float* base = xn + ((size_t)(b * NN) + ch * 64 + p) * DIM + c4 * 4;
    float4 s = {0.f, 0.f, 0.f, 0.f};
    for (int r = 0; r < 32; ++r) {
        float4 v = *(const float4*)(base + (size_t)r * 2 * DIM);
        s.x += v.x; s.y += v.y; s.z += v.z; s.w += v.w;
    }
    *(float4*)red[threadIdx.x] = s;
    __syncthreads();
    if (threadIdx.x < 128) {
        float4 a = *(float4*)red[threadIdx.x];
        float4 c = *(float4*)red[threadIdx.x + 128];
        float4 o = {a.x + c.x, a.y + c.y, a.z + c.z, a.w + c.w};
        *(float4*)(poolpart + (size_t)(b * 16 + ch) * DIM + c4 * 4) = o;
    }
}

__global__ __launch_bounds__(256) void pool2_kernel(
        const float* __restrict__ poolpart, float* __restrict__ pooled) {
    int c = blockIdx.x * 256 + threadIdx.x;
    int b = c >> 9, col = c & 511;
    float s = 0.f;
    for (int ch = 0; ch < 16; ++ch)
        s += poolpart[(size_t)(b * 16 + ch) * DIM + col];
    pooled[c] = s * (1.0f / NN);
}

// ---------------------------------------------------------------------------
// Final MLP split-K (validated R9)
// ---------------------------------------------------------------------------
__global__ __launch_bounds__(256) void ffo1a_kernel(
        const float* __restrict__ pooled, const float* __restrict__ w,
        float* __restrict__ part) {
    int n = blockIdx.x * 256 + threadIdx.x;
    int kc = blockIdx.y;
    float s0 = 0.f, s1 = 0.f, s2 = 0.f, s3 = 0.f;
    for (int k = kc * 128; k < kc * 128 + 128; ++k) {
        float wv = w[(size_t)k * FFH + n];
        s0 = fmaf(pooled[k], wv, s0);
        s1 = fmaf(pooled[512 + k], wv, s1);
        s2 = fmaf(pooled[1024 + k], wv, s2);
        s3 = fmaf(pooled[1536 + k], wv, s3);
    }
    part[(size_t)(kc * 4 + 0) * FFH + n] = s0;
    part[(size_t)(kc * 4 + 1) * FFH + n] = s1;
    part[(size_t)(kc * 4 + 2) * FFH + n] = s2;
    part[(size_t)(kc * 4 + 3) * FFH + n] = s3;
}

__global__ __launch_bounds__(256) void ffo1b_kernel(
        const float* __restrict__ part, const float* __restrict__ bias,
        float* __restrict__ ffoh) {
    int c = blockIdx.x * 256 + threadIdx.x;
    int b = c >> 11, n = c & 2047;
    float s = bias[n];
#pragma unroll
    for (int kc = 0; kc < 4; ++kc)
        s += part[(size_t)(kc * 4 + b) * FFH + n];
    ffoh[c] = gelu_exact(s);
}

__global__ __launch_bounds__(256) void ffo2a_kernel(
        const float* __restrict__ ffoh, const float* __restrict__ w,
        float* __restrict__ part) {
    int n = blockIdx.x * 256 + threadIdx.x;
    int kc = blockIdx.y;
    float s0 = 0.f, s1 = 0.f, s2 = 0.f, s3 = 0.f;
    for (int k = kc * 128; k < kc * 128 + 128; ++k) {
        float wv = w[(size_t)k * DIM + n];
        s0 = fmaf(ffoh[k], wv, s0);
        s1 = fmaf(ffoh[2048 + k], wv, s1);
        s2 = fmaf(ffoh[4096 + k], wv, s2);
        s3 = fmaf(ffoh[6144 + k], wv, s3);
    }
    part[(size_t)(kc * 4 + 0) * DIM + n] = s0;
    part[(size_t)(kc * 4 + 1) * DIM + n] = s1;
    part[(size_t)(kc * 4 + 2) * DIM + n] = s2;
    part[(size_t)(kc * 4 + 3) * DIM + n] = s3;
}

__global__ __launch_bounds__(256) void ffo2b_kernel(
        const float* __restrict__ part, const float* __restrict__ bias,
        float* __restrict__ out) {
    int c = blockIdx.x * 256 + threadIdx.x;
    int b = c >> 9, n = c & 511;
    float s = bias[n];
#pragma unroll
    for (int kc = 0; kc < 16; ++kc)
        s += part[(size_t)(kc * 4 + b) * DIM + n];
    out[c] = s;
}

// ---------------------------------------------------------------------------
// Launch. 256 MiB ws proven (R15); no-alias layout (R16), ~71.7 MB high-water.
// ---------------------------------------------------------------------------
extern "C" void kernel_launch(void* const* d_in, const int* in_sizes, int n_in,
                              void* d_out, int out_size, void* d_ws, size_t ws_size,
                              hipStream_t stream) {
    const float* x       = (const float*)d_in[0];
    const void*  mraw    = d_in[1];
    const float* adj     = (const float*)d_in[2];
    const float* embed_w = (const float*)d_in[3];
    const float* embed_b = (const float*)d_in[4];
    const float* ln1_g   = (const float*)d_in[5];
    const float* ln1_b   = (const float*)d_in[6];
    const float* qkv_w   = (const float*)d_in[7];
    const float* out_w   = (const float*)d_in[8];
    const float* out_b   = (const float*)d_in[9];
    const float* ln2_g   = (const float*)d_in[10];
    const float* ln2_b   = (const float*)d_in[11];
    const float* ff1_w   = (const float*)d_in[12];
    const float* ff1_b   = (const float*)d_in[13];
    const float* ff2_w   = (const float*)d_in[14];
    const float* ff2_b   = (const float*)d_in[15];
    const float* lnout_g = (const float*)d_in[16];
    const float* lnout_b = (const float*)d_in[17];
    const float* ffo1_w  = (const float*)d_in[18];
    const float* ffo1_b  = (const float*)d_in[19];
    const float* ffo2_w  = (const float*)d_in[20];
    const float* ffo2_b  = (const float*)d_in[21];

    char* ws = (char*)d_ws;
    float*          h       = (float*)(ws + 0);
    unsigned short* xnbf    = (unsigned short*)(ws + 8388608);
    unsigned short* adjbf   = (unsigned short*)(ws + 12582912);
    unsigned short* Qb      = (unsigned short*)(ws + 20971520);
    unsigned short* Kb      = (unsigned short*)(ws + 23068672);
    unsigned short* Vtb     = (unsigned short*)(ws + 25165824);
    unsigned short* V2t     = (unsigned short*)(ws + 27262976);
    float*          adjout  = (float*)(ws + 29360128);
    unsigned short* ffh     = (unsigned short*)(ws + 33554432);
    float*          xnf     = (float*)(ws + 50331648);
    unsigned short* attnout = (unsigned short*)(ws + 58720256);
    unsigned short* embedwt = (unsigned short*)(ws + 60555264);
    unsigned short* qkvwt   = (unsigned short*)(ws + 61079552);
    unsigned short* outwt   = (unsigned short*)(ws + 62390272);
    unsigned short* ff1wt   = (unsigned short*)(ws + 62849024);
    unsigned short* ff2wt   = (unsigned short*)(ws + 67043328);
    float*          poolpart= (float*)(ws + 71237632);
    float*          pooled  = (float*)(ws + 71368704);
    float*          ffoh    = (float*)(ws + 71376896);
    float*          part1   = (float*)(ws + 71409664);
    float*          part2   = (float*)(ws + 71540736);
    int*            rowmask = (int*)(ws + 71671808);
    int*            flag    = (int*)(ws + 71688192);

    mask_detect_kernel<<<1, 1024, 0, stream>>>((const unsigned char*)mraw, flag);
    mask_convert_kernel<<<16, 256, 0, stream>>>(mraw, flag, rowmask);
    convx_kernel<<<1024, 256, 0, stream>>>(x, xnbf, ROWS * DIM / 8);
    convw_kernel<<<dim3(8, 8), 256, 0, stream>>>(embed_w, embedwt, 512, 512, 512, 512);
    for (int l = 0; l < 2; ++l) {
        convw_kernel<<<dim3(10, 8), 256, 0, stream>>>(qkv_w + (size_t)l * 512 * 624,
            qkvwt + (size_t)l * QKVNP * 512, 512, 624, 512, QKVNP);
        convw_kernel<<<dim3(8, 4), 256, 0, stream>>>(out_w + (size_t)l * 208 * 512,
            outwt + (size_t)l * 512 * KOUTP, 208, 512, KOUTP, 512);
        convw_kernel<<<dim3(32, 8), 256, 0, stream>>>(ff1_w + (size_t)l * 512 * 2048,
            ff1wt + (size_t)l * 2048 * 512, 512, 2048, 512, 2048);
        convw_kernel<<<dim3(8, 32), 256, 0, stream>>>(ff2_w + (size_t)l * 512 * 2048,
            ff2wt + (size_t)l * 512 * 2048, 2048, 512, 2048, 512);
    }
    zpad_kernel<<<256, 256, 0, stream>>>(attnout);
    padzero_kernel<<<704, 256, 0, stream>>>(Qb, Kb, Vtb, V2t, rowmask);
    adjmask_kernel<<<2048, 256, 0, stream>>>(adj, rowmask, adjbf);

    mm_kernel<0, 64, 64><<<dim3(8, 64, 1), 256, 0, stream>>>(
        xnbf, embedwt, embed_b, h, 512, 512, 512, 0, 0, 0,
        nullptr, nullptr, nullptr, nullptr, nullptr);

    for (int l = 0; l < 2; ++l) {
        ln_kernel<1><<<1024, 256, 0, stream>>>(h, ln1_g + l * DIM, ln1_b + l * DIM, xnbf);
        mm_kernel<3, 64, 64><<<dim3(10, 64, 1), 256, 0, stream>>>(
            xnbf, qkvwt + (size_t)l * QKVNP * 512, nullptr, nullptr,
            512, 512, 0, 0, 0, 0, Qb, Kb, Vtb, V2t, rowmask);
        mm_kernel<0, 64, 64><<<dim3(4, 16, 4), 256, 0, stream>>>(
            adjbf, V2t, nullptr, adjout, 1024, 1024, 256,
            (long long)NN * NN, (long long)256 * NN, (long long)NN * 256,
            nullptr, nullptr, nullptr, nullptr, nullptr);
        attn4_kernel<<<dim3(16, 16, 4), 256, 0, stream>>>(
            Qb, Kb, Vtb, adjout, attnout);
        mm_kernel<2, 64, 64><<<dim3(8, 64, 1), 256, 0, stream>>>(
            attnout, outwt + (size_t)l * 512 * KOUTP, out_b + l * DIM, h,
            KOUTP, KOUTP, 512, 0, 0, 0, nullptr, nullptr, nullptr, nullptr, nullptr);
        ln_kernel<1><<<1024, 256, 0, stream>>>(h, ln2_g + l * DIM, ln2_b + l * DIM, xnbf);
        mm_kernel<1, 128, 128><<<dim3(16, 32, 1), 256, 0, stream>>>(
            xnbf, ff1wt + (size_t)l * 2048 * 512, ff1_b + l * FFH, ffh,
            512, 512, 2048, 0, 0, 0, nullptr, nullptr, nullptr, nullptr, nullptr);
        mm_kernel<2, 64, 64><<<dim3(8, 64, 1), 256, 0, stream>>>(
            ffh, ff2wt + (size_t)l * 512 * 2048, ff2_b + l * DIM, h,
            2048, 2048, 512, 0, 0, 0, nullptr, nullptr, nullptr, nullptr, nullptr);
    }

    ln_kernel<0><<<1024, 256, 0, stream>>>(h, lnout_g, lnout_b, xnf);
    pool1_kernel<<<dim3(16, 4), 256, 0, stream>>>(xnf, poolpart);
    pool2_kernel<<<8, 256, 0, stream>>>(poolpart, pooled);
    ffo1a_kernel<<<dim3(8, 4), 256, 0, stream>>>(pooled, ffo1_w, part1);
    ffo1b_kernel<<<32, 256, 0, stream>>>(part1, ffo1_b, ffoh);
    ffo2a_kernel<<<dim3(2, 16), 256, 0, stream>>>(ffoh, ffo2_w, part2);
    ffo2b_kernel<<<8, 256, 0, stream>>>(part2, ffo2_b, (float*)d_out);
}

// Round 20
// 363.653 us; speedup vs baseline: 1.0742x; 1.0164x over previous
//
#include <hip/hip_runtime.h>
#include <math.h>

#define BB    4
#define NN    1024
#define DIM   512
#define HH    16
#define DH    13
#define INNER 208
#define QKVN  624
#define QKVNP 640
#define KOUTP 224
#define FFH   2048
#define ROWS  4096

typedef __attribute__((ext_vector_type(8))) short short8v;
typedef __attribute__((ext_vector_type(4))) float f32x4;

// softmax scale * log2(e), baked into Q at scatter time (R17, validated)
#define QSCL (0.27735009811261457f * 1.4426950408889634f)

__device__ __forceinline__ unsigned short f2bf(float f) {
    union { float f; unsigned int u; } x; x.f = f;
    unsigned int u = x.u + 0x7FFFu + ((x.u >> 16) & 1u);
    return (unsigned short)(u >> 16);
}
__device__ __forceinline__ float bf2f(unsigned short s) {
    union { unsigned int u; float f; } x; x.u = ((unsigned int)s) << 16;
    return x.f;
}
__device__ __forceinline__ float gelu_exact(float x) {
    return 0.5f * x * (1.0f + erff(x * 0.70710678118654752f));
}

// ---------------------------------------------------------------------------
// Mask dtype detection (validated R4+)
// ---------------------------------------------------------------------------
__global__ __launch_bounds__(1024) void mask_detect_kernel(
        const unsigned char* __restrict__ mraw, int* __restrict__ flag) {
    __shared__ int any;
    if (threadIdx.x == 0) any = 0;
    __syncthreads();
    int t = threadIdx.x;
    int v = mraw[4 * t + 1] | mraw[4 * t + 2] | mraw[4 * t + 3];
    if (v) atomicOr(&any, 1);
    __syncthreads();
    if (threadIdx.x == 0) *flag = any;
}

__device__ __forceinline__ int mask_at(const void* mraw, int fl, int i) {
    if (fl) return ((const unsigned char*)mraw)[i] != 0;
    return ((const int*)mraw)[i] != 0;
}

// ---------------------------------------------------------------------------
// Fused setup (R20): rowmask + attnout pad + Q/K mask lanes + V pad zeroing.
// Mask values read directly from mraw (no intra-kernel dependency).
//  Qb[bh][n][13] = mi ? 1 : 0 ; Kb[bh][rr(n)][13] = mj ? 0 : -128 (R19 fold)
// ---------------------------------------------------------------------------
__global__ __launch_bounds__(256) void setup_kernel(
        const void* __restrict__ mraw, const int* __restrict__ flag,
        int* __restrict__ rowmask, unsigned short* __restrict__ attnout,
        unsigned short* __restrict__ Qb, unsigned short* __restrict__ Kb,
        unsigned short* __restrict__ Vtb, unsigned short* __restrict__ V2t) {
    int idx = blockIdx.x * 256 + threadIdx.x;       // 249856 total
    int fl = *flag;
    if (idx < 4096) {
        rowmask[idx] = mask_at(mraw, fl, idx);
    } else if (idx < 69632) {
        int i = idx - 4096;
        int row = i >> 4, c = INNER + (i & 15);
        attnout[(size_t)row * KOUTP + c] = 0;
    } else if (idx < 135168) {
        int i = idx - 69632;                        // Qb: bh*1024+n
        int bh = i >> 10, n = i & 1023;
        int mi = mask_at(mraw, fl, (bh >> 4) * NN + n);
        unsigned short* p = Qb + (size_t)i * 16 + 13;
        p[0] = mi ? f2bf(1.0f) : (unsigned short)0;
        p[1] = 0; p[2] = 0;
    } else if (idx < 200704) {
        int i = idx - 135168;
        int bh = i >> 10, n = i & 1023;
        int mj = mask_at(mraw, fl, (bh >> 4) * NN + n);
        int rr = (n & ~31) | (((n >> 2) & 1) << 4)
               | (((n >> 3) & 3) << 2) | (n & 3);
        unsigned short* p = Kb + ((size_t)bh * NN + rr) * 16 + 13;
        p[0] = mj ? (unsigned short)0 : f2bf(-128.0f);
        p[1] = 0; p[2] = 0;
    } else if (idx < 225280) {
        int i = idx - 200704;
        int bh = i / 384, r = (i >> 7) % 3, c = i & 127;
        *(uint4*)(Vtb + ((size_t)(bh * 16 + 13 + r) * 1024 + c * 8)) =
            (uint4){0u, 0u, 0u, 0u};
    } else if (idx < 249856) {
        int i = idx - 225280;
        int b = i / 6144, r = (i >> 7) % 48, c = i & 127;
        *(uint4*)(V2t + ((size_t)(b * 256 + 208 + r) * 1024 + c * 8)) =
            (uint4){0u, 0u, 0u, 0u};
    }
}

// ---------------------------------------------------------------------------
// Weight transpose-convert (validated R7+)
// ---------------------------------------------------------------------------
__global__ __launch_bounds__(256) void convw_kernel(
        const float* __restrict__ src, unsigned short* __restrict__ dst,
        int srcK, int srcN, int dstK, int dstN) {
    __shared__ float t[64][65];
    const int n0 = blockIdx.x * 64, k0 = blockIdx.y * 64;
    const int tq = threadIdx.x & 15, tr = threadIdx.x >> 4;
#pragma unroll
    for (int it = 0; it < 4; ++it) {
        int kl = tr + it * 16;
        int kg = k0 + kl;
        int ng = n0 + tq * 4;
        float4 v = {0.f, 0.f, 0.f, 0.f};
        if (kg < srcK) {
            const float* sp = src + (size_t)kg * srcN;
            if (ng + 3 < srcN) v = *(const float4*)(sp + ng);
            else {
                if (ng + 0 < srcN) v.x = sp[ng + 0];
                if (ng + 1 < srcN) v.y = sp[ng + 1];
                if (ng + 2 < srcN) v.z = sp[ng + 2];
                if (ng + 3 < srcN) v.w = sp[ng + 3];
            }
        }
        t[kl][tq * 4 + 0] = v.x; t[kl][tq * 4 + 1] = v.y;
        t[kl][tq * 4 + 2] = v.z; t[kl][tq * 4 + 3] = v.w;
    }
    __syncthreads();
#pragma unroll
    for (int it = 0; it < 4; ++it) {
        int nl = tr + it * 16;
        int ng = n0 + nl;
        int kg = k0 + tq * 4;
        if (ng < dstN && kg < dstK) {
            ushort4 o;
            o.x = f2bf(t[tq * 4 + 0][nl]); o.y = f2bf(t[tq * 4 + 1][nl]);
            o.z = f2bf(t[tq * 4 + 2][nl]); o.w = f2bf(t[tq * 4 + 3][nl]);
            *(ushort4*)(dst + (size_t)ng * dstK + kg) = o;
        }
    }
}

__global__ __launch_bounds__(256) void convx_kernel(
        const float* __restrict__ src, unsigned short* __restrict__ dst, int n8) {
    int idx = blockIdx.x * 256 + threadIdx.x;
    if (idx >= n8) return;
    float4 a = ((const float4*)src)[idx * 2];
    float4 b = ((const float4*)src)[idx * 2 + 1];
    uint4 o;
    o.x = (unsigned)f2bf(a.x) | ((unsigned)f2bf(a.y) << 16);
    o.y = (unsigned)f2bf(a.z) | ((unsigned)f2bf(a.w) << 16);
    o.z = (unsigned)f2bf(b.x) | ((unsigned)f2bf(b.y) << 16);
    o.w = (unsigned)f2bf(b.z) | ((unsigned)f2bf(b.w) << 16);
    ((uint4*)dst)[idx] = o;
}

__global__ __launch_bounds__(256) void adjmask_kernel(
        const float* __restrict__ adj, const int* __restrict__ rmask,
        unsigned short* __restrict__ adjbf) {
    int idx = blockIdx.x * 256 + threadIdx.x;
    int j8 = idx & 127;
    int row = idx >> 7;
    int b = row >> 10;
    int mi = rmask[row];
    const float* ap = adj + (size_t)row * NN + j8 * 8;
    const int* rm = rmask + (b << 10) + j8 * 8;
    float4 a0 = *(const float4*)ap, a1 = *(const float4*)(ap + 4);
    unsigned short o[8];
    o[0] = (mi && rm[0]) ? f2bf(a0.x) : 0;
    o[1] = (mi && rm[1]) ? f2bf(a0.y) : 0;
    o[2] = (mi && rm[2]) ? f2bf(a0.z) : 0;
    o[3] = (mi && rm[3]) ? f2bf(a0.w) : 0;
    o[4] = (mi && rm[4]) ? f2bf(a1.x) : 0;
    o[5] = (mi && rm[5]) ? f2bf(a1.y) : 0;
    o[6] = (mi && rm[6]) ? f2bf(a1.z) : 0;
    o[7] = (mi && rm[7]) ? f2bf(a1.w) : 0;
    uint4 pk;
    pk.x = (unsigned)o[0] | ((unsigned)o[1] << 16);
    pk.y = (unsigned)o[2] | ((unsigned)o[3] << 16);
    pk.z = (unsigned)o[4] | ((unsigned)o[5] << 16);
    pk.w = (unsigned)o[6] | ((unsigned)o[7] << 16);
    *(uint4*)(adjbf + (size_t)row * NN + j8 * 8) = pk;
}

// ---------------------------------------------------------------------------
// MFMA bf16 GEMM (validated R14-R19). EPI: 0 f32 store | 1 gelu->bf16 |
// 2 bias+add f32 | 3 qkv scatter (Q pre-scaled, d<13 only) | 4 bf16 store
// (batched, no bias) [R20: adjout].
// ---------------------------------------------------------------------------
template<int EPI, int BM, int BN>
__global__ __launch_bounds__(256) void mm_kernel(
        const unsigned short* __restrict__ A, const unsigned short* __restrict__ W,
        const float* __restrict__ bias, void* __restrict__ Cdst,
        int K, int lda, int ldc,
        long long aBatch, long long bBatch, long long cBatch,
        unsigned short* __restrict__ Qb, unsigned short* __restrict__ Kb,
        unsigned short* __restrict__ Vtb, unsigned short* __restrict__ V2t,
        const int* __restrict__ qmask)
{
    constexpr int MF = BM / 32;
    constexpr int NF = BN / 32;
    constexpr int AROUNDS = BM / 64;
    constexpr int BROUNDS = BN / 64;
    __shared__ unsigned short As[BM * 32];
    __shared__ unsigned short Bs[BN * 32];
    const int tid = threadIdx.x;
    const int m0 = blockIdx.y * BM;
    const int n0 = blockIdx.x * BN;
    const int z  = blockIdx.z;

    const int lane = tid & 63;
    const int wv = tid >> 6;
    const int wvbase = wv << 6;
    const int wm = wv >> 1, wn = wv & 1;
    const int lrow = lane & 15, kgrp = lane >> 4;

    f32x4 acc[MF][NF];
#pragma unroll
    for (int i = 0; i < MF; ++i)
#pragma unroll
        for (int j = 0; j < NF; ++j) acc[i][j] = (f32x4){0.f, 0.f, 0.f, 0.f};

    const unsigned short* Ab = A + (size_t)z * aBatch;
    const unsigned short* Wb = W + (size_t)z * bBatch;

    for (int k0 = 0; k0 < K; k0 += 32) {
#pragma unroll
        for (int r = 0; r < AROUNDS; ++r) {
            int c = r * 256 + tid;
            const unsigned short* g = Ab + (size_t)(m0 + (c >> 2)) * lda + k0 + (c & 3) * 8;
            __builtin_amdgcn_global_load_lds((const unsigned int*)g,
                (unsigned int*)&As[(r * 256 + wvbase) * 8], 16, 0, 0);
        }
#pragma unroll
        for (int r = 0; r < BROUNDS; ++r) {
            int c = r * 256 + tid;
            const unsigned short* g = Wb + (size_t)(n0 + (c >> 2)) * K + k0 + (c & 3) * 8;
            __builtin_amdgcn_global_load_lds((const unsigned int*)g,
                (unsigned int*)&Bs[(r * 256 + wvbase) * 8], 16, 0, 0);
        }
        __syncthreads();
        short8v af[MF], bfv[NF];
#pragma unroll
        for (int f = 0; f < MF; ++f)
            af[f] = *(const short8v*)&As[(wm * (BM / 2) + f * 16 + lrow) * 32 + kgrp * 8];
#pragma unroll
        for (int f = 0; f < NF; ++f)
            bfv[f] = *(const short8v*)&Bs[(wn * (BN / 2) + f * 16 + lrow) * 32 + kgrp * 8];
#pragma unroll
        for (int fi = 0; fi < MF; ++fi)
#pragma unroll
            for (int fj = 0; fj < NF; ++fj)
                acc[fi][fj] = __builtin_amdgcn_mfma_f32_16x16x32_bf16(
                    af[fi], bfv[fj], acc[fi][fj], 0, 0, 0);
        __syncthreads();
    }

#pragma unroll
    for (int fi = 0; fi < MF; ++fi) {
#pragma unroll
        for (int fj = 0; fj < NF; ++fj) {
#pragma unroll
            for (int p = 0; p < 4; ++p) {
                int row = m0 + wm * (BM / 2) + fi * 16 + kgrp * 4 + p;
                int col = n0 + wn * (BN / 2) + fj * 16 + lrow;
                float v = acc[fi][fj][p];
                if (EPI == 0) {
                    float* C = (float*)Cdst + (size_t)z * cBatch;
                    if (bias) v += bias[col];
                    C[(size_t)row * ldc + col] = v;
                } else if (EPI == 1) {
                    unsigned short* C = (unsigned short*)Cdst;
                    C[(size_t)row * ldc + col] = f2bf(gelu_exact(v + bias[col]));
                } else if (EPI == 2) {
                    float* C = (float*)Cdst;
                    C[(size_t)row * ldc + col] += v + bias[col];
                } else if (EPI == 4) {
                    unsigned short* C = (unsigned short*)Cdst + (size_t)z * cBatch;
                    C[(size_t)row * ldc + col] = f2bf(v);
                } else {
                    if (col < QKVN) {
                        int hh  = col / 39;
                        int rem = col - hh * 39;
                        int sel = rem / 13;
                        int d   = rem - sel * 13;
                        int bb = row >> 10, n = row & (NN - 1);
                        int bh = bb * HH + hh;
                        if (sel == 0) {
                            float qs = qmask[row] ? QSCL : 0.0f;
                            Qb[((size_t)bh * NN + n) * 16 + d] = f2bf(v * qs);
                        } else if (sel == 1) {
                            int rr = (n & ~31) | (((n >> 2) & 1) << 4)
                                   | (((n >> 3) & 3) << 2) | (n & 3);
                            Kb[((size_t)bh * NN + rr) * 16 + d] = f2bf(v);
                        } else {
                            unsigned short bv = f2bf(v);
                            Vtb[((size_t)bh * 16 + d) * NN + n] = bv;
                            V2t[((size_t)bb * 256 + hh * 13 + d) * NN + n] = bv;
                        }
                    }
                }
            }
        }
    }
}

// ---------------------------------------------------------------------------
// LayerNorm (unchanged)
// ---------------------------------------------------------------------------
template<int BFOUT>
__global__ __launch_bounds__(256) void ln_kernel(
        const float* __restrict__ x, const float* __restrict__ g,
        const float* __restrict__ bta, void* __restrict__ y) {
    const int lane = threadIdx.x & 63;
    const int row = (blockIdx.x * 256 + threadIdx.x) >> 6;
    const float* xp = x + (size_t)row * DIM + lane * 8;
    float4 v0 = *(const float4*)(xp);
    float4 v1 = *(const float4*)(xp + 4);
    float s = v0.x + v0.y + v0.z + v0.w + v1.x + v1.y + v1.z + v1.w;
#pragma unroll
    for (int off = 32; off >= 1; off >>= 1) s += __shfl_xor(s, off);
    float mean = s * (1.0f / DIM);
    float q =
        (v0.x - mean) * (v0.x - mean) + (v0.y - mean) * (v0.y - mean) +
        (v0.z - mean) * (v0.z - mean) + (v0.w - mean) * (v0.w - mean) +
        (v1.x - mean) * (v1.x - mean) + (v1.y - mean) * (v1.y - mean) +
        (v1.z - mean) * (v1.z - mean) + (v1.w - mean) * (v1.w - mean);
#pragma unroll
    for (int off = 32; off >= 1; off >>= 1) q += __shfl_xor(q, off);
    float rstd = rsqrtf(q * (1.0f / DIM) + 1e-5f);
    const int c = lane * 8;
    float4 g0 = *(const float4*)(g + c), g1 = *(const float4*)(g + c + 4);
    float4 b0 = *(const float4*)(bta + c), b1 = *(const float4*)(bta + c + 4);
    float o0 = (v0.x - mean) * rstd * g0.x + b0.x;
    float o1 = (v0.y - mean) * rstd * g0.y + b0.y;
    float o2 = (v0.z - mean) * rstd * g0.z + b0.z;
    float o3 = (v0.w - mean) * rstd * g0.w + b0.w;
    float o4 = (v1.x - mean) * rstd * g1.x + b1.x;
    float o5 = (v1.y - mean) * rstd * g1.y + b1.y;
    float o6 = (v1.z - mean) * rstd * g1.z + b1.z;
    float o7 = (v1.w - mean) * rstd * g1.w + b1.w;
    if (BFOUT) {
        unsigned short* yp = (unsigned short*)y + (size_t)row * DIM + c;
        uint4 o;
        o.x = (unsigned)f2bf(o0) | ((unsigned)f2bf(o1) << 16);
        o.y = (unsigned)f2bf(o2) | ((unsigned)f2bf(o3) << 16);
        o.z = (unsigned)f2bf(o4) | ((unsigned)f2bf(o5) << 16);
        o.w = (unsigned)f2bf(o6) | ((unsigned)f2bf(o7) << 16);
        *(uint4*)yp = o;
    } else {
        float* yp = (float*)y + (size_t)row * DIM + c;
        *(float4*)(yp)     = (float4){o0, o1, o2, o3};
        *(float4*)(yp + 4) = (float4){o4, o5, o6, o7};
    }
}

// ---------------------------------------------------------------------------
// attn4 v6 (R20): R19 mask-fold + unroll 4 + bf16 adjout read.
// ---------------------------------------------------------------------------
__global__ __launch_bounds__(256) void attn4_kernel(
        const unsigned short* __restrict__ Qb, const unsigned short* __restrict__ Kb,
        const unsigned short* __restrict__ Vtb, const unsigned short* __restrict__ adjoutb,
        unsigned short* __restrict__ attnout) {
    const int tid = threadIdx.x;
    const int qt = blockIdx.x, h = blockIdx.y, b = blockIdx.z;
    const int bh = b * HH + h;
    const int wv = tid >> 6, lane = tid & 63;
    const int lrow = lane & 15, g = lane >> 4;
    const int q = qt * 64 + wv * 16 + lrow;

    short8v qf = (short8v){0, 0, 0, 0, 0, 0, 0, 0};
    if (g < 2)
        qf = *(const short8v*)(Qb + ((size_t)bh * NN + q) * 16 + g * 8);

    const unsigned short* Kbh = Kb + (size_t)bh * NN * 16;
    const unsigned short* Vrow = Vtb + ((size_t)bh * 16 + lrow) * NN;

    f32x4 oacc = (f32x4){0.f, 0.f, 0.f, 0.f};
    float zacc = 0.0f;

#pragma unroll 4
    for (int t = 0; t < 32; ++t) {
        const int j0 = t * 32;
        short8v kf0 = (short8v){0, 0, 0, 0, 0, 0, 0, 0};
        short8v kf1 = (short8v){0, 0, 0, 0, 0, 0, 0, 0};
        if (g < 2) {
            kf0 = *(const short8v*)(Kbh + (size_t)(j0 + lrow) * 16 + g * 8);
            kf1 = *(const short8v*)(Kbh + (size_t)(j0 + 16 + lrow) * 16 + g * 8);
        }
        f32x4 s0 = (f32x4){0.f, 0.f, 0.f, 0.f};
        f32x4 s1 = (f32x4){0.f, 0.f, 0.f, 0.f};
        s0 = __builtin_amdgcn_mfma_f32_16x16x32_bf16(kf0, qf, s0, 0, 0, 0);
        s1 = __builtin_amdgcn_mfma_f32_16x16x32_bf16(kf1, qf, s1, 0, 0, 0);
        float w0 = exp2f(fminf(s0[0], 80.f));
        float w1 = exp2f(fminf(s0[1], 80.f));
        float w2 = exp2f(fminf(s0[2], 80.f));
        float w3 = exp2f(fminf(s0[3], 80.f));
        float w4 = exp2f(fminf(s1[0], 80.f));
        float w5 = exp2f(fminf(s1[1], 80.f));
        float w6 = exp2f(fminf(s1[2], 80.f));
        float w7 = exp2f(fminf(s1[3], 80.f));
        zacc += ((w0 + w1) + (w2 + w3)) + ((w4 + w5) + (w6 + w7));
        unsigned p01, p23, p45, p67;
        asm("v_cvt_pk_bf16_f32 %0, %1, %2" : "=v"(p01) : "v"(w0), "v"(w1));
        asm("v_cvt_pk_bf16_f32 %0, %1, %2" : "=v"(p23) : "v"(w2), "v"(w3));
        asm("v_cvt_pk_bf16_f32 %0, %1, %2" : "=v"(p45) : "v"(w4), "v"(w5));
        asm("v_cvt_pk_bf16_f32 %0, %1, %2" : "=v"(p67) : "v"(w6), "v"(w7));
        union { uint4 u4; short8v s8; } pu;
        pu.u4 = (uint4){p01, p23, p45, p67};
        short8v vf = *(const short8v*)(Vrow + j0 + g * 8);
        oacc = __builtin_amdgcn_mfma_f32_16x16x32_bf16(vf, pu.s8, oacc, 0, 0, 0);
    }

    zacc += __shfl_xor(zacc, 16);
    zacc += __shfl_xor(zacc, 32);
    float inv = 1.0f / zacc;

    const unsigned short* arow = adjoutb + ((size_t)(b * NN + q)) * 256 + h * 13;
    unsigned short* orow = attnout + (size_t)(b * NN + q) * KOUTP + h * 13;
#pragma unroll
    for (int p = 0; p < 4; ++p) {
        int d = 4 * g + p;
        if (d < 13)
            orow[d] = f2bf(fmaf(oacc[p], inv, 0.5f * bf2f(arow[d])));
    }
}

// ---------------------------------------------------------------------------
// Coalesced pool (unchanged)
// ---------------------------------------------------------------------------
__global__ __launch_bounds__(256) void pool1_kernel(
        const float* __restrict__ xn, float* __restrict__ poolpart) {
    __shared__ float red[256][4];
    const int ch = blockIdx.x, b = blockIdx.y;
    const int c4 = threadIdx.x & 127, p = threadIdx.x >> 7;
    const float* base = xn + ((size_t)(b * NN) + ch * 64 + p) * DIM + c4 * 4;
    float4 s = {0.f, 0.f, 0.f, 0.f};
    for (int r = 0; r < 32; ++r) {
        float4 v = *(const float4*)(base + (size_t)r * 2 * DIM);
        s.x += v.x; s.y += v.y; s.z += v.z; s.w += v.w;
    }
    *(float4*)red[threadIdx.x] = s;
    __syncthreads();
    if (threadIdx.x < 128) {
        float4 a = *(float4*)red[threadIdx.x];
        float4 c = *(float4*)red[threadIdx.x + 128];
        float4 o = {a.x + c.x, a.y + c.y, a.z + c.z, a.w + c.w};
        *(float4*)(poolpart + (size_t)(b * 16 + ch) * DIM + c4 * 4) = o;
    }
}

__global__ __launch_bounds__(256) void pool2_kernel(
        const float* __restrict__ poolpart, float* __restrict__ pooled) {
    int c = blockIdx.x * 256 + threadIdx.x;
    int b = c >> 9, col = c & 511;
    float s = 0.f;
    for (int ch = 0; ch < 16; ++ch)
        s += poolpart[(size_t)(b * 16 + ch) * DIM + col];
    pooled[c] = s * (1.0f / NN);
}

// ---------------------------------------------------------------------------
// Final MLP split-K (validated R9)
// ---------------------------------------------------------------------------
__global__ __launch_bounds__(256) void ffo1a_kernel(
        const float* __restrict__ pooled, const float* __restrict__ w,
        float* __restrict__ part) {
    int n = blockIdx.x * 256 + threadIdx.x;
    int kc = blockIdx.y;
    float s0 = 0.f, s1 = 0.f, s2 = 0.f, s3 = 0.f;
    for (int k = kc * 128; k < kc * 128 + 128; ++k) {
        float wv = w[(size_t)k * FFH + n];
        s0 = fmaf(pooled[k], wv, s0);
        s1 = fmaf(pooled[512 + k], wv, s1);
        s2 = fmaf(pooled[1024 + k], wv, s2);
        s3 = fmaf(pooled[1536 + k], wv, s3);
    }
    part[(size_t)(kc * 4 + 0) * FFH + n] = s0;
    part[(size_t)(kc * 4 + 1) * FFH + n] = s1;
    part[(size_t)(kc * 4 + 2) * FFH + n] = s2;
    part[(size_t)(kc * 4 + 3) * FFH + n] = s3;
}

__global__ __launch_bounds__(256) void ffo1b_kernel(
        const float* __restrict__ part, const float* __restrict__ bias,
        float* __restrict__ ffoh) {
    int c = blockIdx.x * 256 + threadIdx.x;
    int b = c >> 11, n = c & 2047;
    float s = bias[n];
#pragma unroll
    for (int kc = 0; kc < 4; ++kc)
        s += part[(size_t)(kc * 4 + b) * FFH + n];
    ffoh[c] = gelu_exact(s);
}

__global__ __launch_bounds__(256) void ffo2a_kernel(
        const float* __restrict__ ffoh, const float* __restrict__ w,
        float* __restrict__ part) {
    int n = blockIdx.x * 256 + threadIdx.x;
    int kc = blockIdx.y;
    float s0 = 0.f, s1 = 0.f, s2 = 0.f, s3 = 0.f;
    for (int k = kc * 128; k < kc * 128 + 128; ++k) {
        float wv = w[(size_t)k * DIM + n];
        s0 = fmaf(ffoh[k], wv, s0);
        s1 = fmaf(ffoh[2048 + k], wv, s1);
        s2 = fmaf(ffoh[4096 + k], wv, s2);
        s3 = fmaf(ffoh[6144 + k], wv, s3);
    }
    part[(size_t)(kc * 4 + 0) * DIM + n] = s0;
    part[(size_t)(kc * 4 + 1) * DIM + n] = s1;
    part[(size_t)(kc * 4 + 2) * DIM + n] = s2;
    part[(size_t)(kc * 4 + 3) * DIM + n] = s3;
}

__global__ __launch_bounds__(256) void ffo2b_kernel(
        const float* __restrict__ part, const float* __restrict__ bias,
        float* __restrict__ out) {
    int c = blockIdx.x * 256 + threadIdx.x;
    int b = c >> 9, n = c & 511;
    float s = bias[n];
#pragma unroll
    for (int kc = 0; kc < 16; ++kc)
        s += part[(size_t)(kc * 4 + b) * DIM + n];
    out[c] = s;
}

// ---------------------------------------------------------------------------
// Launch. 256 MiB ws proven (R15); no-alias layout (R16), ~71.7 MB high-water.
// ---------------------------------------------------------------------------
extern "C" void kernel_launch(void* const* d_in, const int* in_sizes, int n_in,
                              void* d_out, int out_size, void* d_ws, size_t ws_size,
                              hipStream_t stream) {
    const float* x       = (const float*)d_in[0];
    const void*  mraw    = d_in[1];
    const float* adj     = (const float*)d_in[2];
    const float* embed_w = (const float*)d_in[3];
    const float* embed_b = (const float*)d_in[4];
    const float* ln1_g   = (const float*)d_in[5];
    const float* ln1_b   = (const float*)d_in[6];
    const float* qkv_w   = (const float*)d_in[7];
    const float* out_w   = (const float*)d_in[8];
    const float* out_b   = (const float*)d_in[9];
    const float* ln2_g   = (const float*)d_in[10];
    const float* ln2_b   = (const float*)d_in[11];
    const float* ff1_w   = (const float*)d_in[12];
    const float* ff1_b   = (const float*)d_in[13];
    const float* ff2_w   = (const float*)d_in[14];
    const float* ff2_b   = (const float*)d_in[15];
    const float* lnout_g = (const float*)d_in[16];
    const float* lnout_b = (const float*)d_in[17];
    const float* ffo1_w  = (const float*)d_in[18];
    const float* ffo1_b  = (const float*)d_in[19];
    const float* ffo2_w  = (const float*)d_in[20];
    const float* ffo2_b  = (const float*)d_in[21];

    char* ws = (char*)d_ws;
    float*          h       = (float*)(ws + 0);
    unsigned short* xnbf    = (unsigned short*)(ws + 8388608);
    unsigned short* adjbf   = (unsigned short*)(ws + 12582912);
    unsigned short* Qb      = (unsigned short*)(ws + 20971520);
    unsigned short* Kb      = (unsigned short*)(ws + 23068672);
    unsigned short* Vtb     = (unsigned short*)(ws + 25165824);
    unsigned short* V2t     = (unsigned short*)(ws + 27262976);
    unsigned short* adjoutb = (unsigned short*)(ws + 29360128);  // 2 MB bf16
    unsigned short* ffh     = (unsigned short*)(ws + 33554432);
    float*          xnf     = (float*)(ws + 50331648);
    unsigned short* attnout = (unsigned short*)(ws + 58720256);
    unsigned short* embedwt = (unsigned short*)(ws + 60555264);
    unsigned short* qkvwt   = (unsigned short*)(ws + 61079552);
    unsigned short* outwt   = (unsigned short*)(ws + 62390272);
    unsigned short* ff1wt   = (unsigned short*)(ws + 62849024);
    unsigned short* ff2wt   = (unsigned short*)(ws + 67043328);
    float*          poolpart= (float*)(ws + 71237632);
    float*          pooled  = (float*)(ws + 71368704);
    float*          ffoh    = (float*)(ws + 71376896);
    float*          part1   = (float*)(ws + 71409664);
    float*          part2   = (float*)(ws + 71540736);
    int*            rowmask = (int*)(ws + 71671808);
    int*            flag    = (int*)(ws + 71688192);

    mask_detect_kernel<<<1, 1024, 0, stream>>>((const unsigned char*)mraw, flag);
    setup_kernel<<<976, 256, 0, stream>>>(mraw, flag, rowmask, attnout,
                                          Qb, Kb, Vtb, V2t);
    convx_kernel<<<1024, 256, 0, stream>>>(x, xnbf, ROWS * DIM / 8);
    convw_kernel<<<dim3(8, 8), 256, 0, stream>>>(embed_w, embedwt, 512, 512, 512, 512);
    for (int l = 0; l < 2; ++l) {
        convw_kernel<<<dim3(10, 8), 256, 0, stream>>>(qkv_w + (size_t)l * 512 * 624,
            qkvwt + (size_t)l * QKVNP * 512, 512, 624, 512, QKVNP);
        convw_kernel<<<dim3(8, 4), 256, 0, stream>>>(out_w + (size_t)l * 208 * 512,
            outwt + (size_t)l * 512 * KOUTP, 208, 512, KOUTP, 512);
        convw_kernel<<<dim3(32, 8), 256, 0, stream>>>(ff1_w + (size_t)l * 512 * 2048,
            ff1wt + (size_t)l * 2048 * 512, 512, 2048, 512, 2048);
        convw_kernel<<<dim3(8, 32), 256, 0, stream>>>(ff2_w + (size_t)l * 512 * 2048,
            ff2wt + (size_t)l * 512 * 2048, 2048, 512, 2048, 512);
    }
    adjmask_kernel<<<2048, 256, 0, stream>>>(adj, rowmask, adjbf);

    mm_kernel<0, 64, 64><<<dim3(8, 64, 1), 256, 0, stream>>>(
        xnbf, embedwt, embed_b, h, 512, 512, 512, 0, 0, 0,
        nullptr, nullptr, nullptr, nullptr, nullptr);

    for (int l = 0; l < 2; ++l) {
        ln_kernel<1><<<1024, 256, 0, stream>>>(h, ln1_g + l * DIM, ln1_b + l * DIM, xnbf);
        mm_kernel<3, 64, 64><<<dim3(10, 64, 1), 256, 0, stream>>>(
            xnbf, qkvwt + (size_t)l * QKVNP * 512, nullptr, nullptr,
            512, 512, 0, 0, 0, 0, Qb, Kb, Vtb, V2t, rowmask);
        mm_kernel<4, 64, 64><<<dim3(4, 16, 4), 256, 0, stream>>>(
            adjbf, V2t, nullptr, adjoutb, 1024, 1024, 256,
            (long long)NN * NN, (long long)256 * NN, (long long)NN * 256,
            nullptr, nullptr, nullptr, nullptr, nullptr);
        attn4_kernel<<<dim3(16, 16, 4), 256, 0, stream>>>(
            Qb, Kb, Vtb, adjoutb, attnout);
        mm_kernel<2, 64, 64><<<dim3(8, 64, 1), 256, 0, stream>>>(
            attnout, outwt + (size_t)l * 512 * KOUTP, out_b + l * DIM, h,
            KOUTP, KOUTP, 512, 0, 0, 0, nullptr, nullptr, nullptr, nullptr, nullptr);
        ln_kernel<1><<<1024, 256, 0, stream>>>(h, ln2_g + l * DIM, ln2_b + l * DIM, xnbf);
        mm_kernel<1, 128, 128><<<dim3(16, 32, 1), 256, 0, stream>>>(
            xnbf, ff1wt + (size_t)l * 2048 * 512, ff1_b + l * FFH, ffh,
            512, 512, 2048, 0, 0, 0, nullptr, nullptr, nullptr, nullptr, nullptr);
        mm_kernel<2, 64, 64><<<dim3(8, 64, 1), 256, 0, stream>>>(
            ffh, ff2wt + (size_t)l * 512 * 2048, ff2_b + l * DIM, h,
            2048, 2048, 512, 0, 0, 0, nullptr, nullptr, nullptr, nullptr, nullptr);
    }

    ln_kernel<0><<<1024, 256, 0, stream>>>(h, lnout_g, lnout_b, xnf);
    pool1_kernel<<<dim3(16, 4), 256, 0, stream>>>(xnf, poolpart);
    pool2_kernel<<<8, 256, 0, stream>>>(poolpart, pooled);
    ffo1a_kernel<<<dim3(8, 4), 256, 0, stream>>>(pooled, ffo1_w, part1);
    ffo1b_kernel<<<32, 256, 0, stream>>>(part1, ffo1_b, ffoh);
    ffo2a_kernel<<<dim3(2, 16), 256, 0, stream>>>(ffoh, ffo2_w, part2);
    ffo2b_kernel<<<8, 256, 0, stream>>>(part2, ffo2_b, (float*)d_out);
}